// Round 2
// baseline (823.862 us; speedup 1.0000x reference)
//
#include <hip/hip_runtime.h>
#include <math.h>

#define NPTS 2048
#define NBATCH 8
#define MTOT (NBATCH*NPTS)
#define KNB 32
#define NNC 32
#define FDIM 96
#define KCONV 3072
#define OUTC 64

__device__ __forceinline__ unsigned short f2bf(float f) {
    unsigned u = __float_as_uint(f);
    unsigned r = u + 0x7FFFu + ((u >> 16) & 1u);
    return (unsigned short)(r >> 16);
}
__device__ __forceinline__ float bflo(unsigned u) { return __uint_as_float(u << 16); }
__device__ __forceinline__ float bfhi(unsigned u) { return __uint_as_float(u & 0xFFFF0000u); }

// ---- KNN: top-32 by fp64 pair value (desc), index asc tie-break ----------
__global__ __launch_bounds__(256) void knn_kernel(const float* __restrict__ x,
                                                  int* __restrict__ idxout) {
    __shared__ float xs[NPTS], ys[NPTS], zs[NPTS];
    int t = threadIdx.x;
    int b = blockIdx.x / (NPTS / 4);
    int grp = blockIdx.x % (NPTS / 4);
    const float* xb = x + (size_t)b * 3 * NPTS;
    for (int i = t; i < NPTS; i += 256) {
        xs[i] = xb[i]; ys[i] = xb[NPTS + i]; zs[i] = xb[2 * NPTS + i];
    }
    __syncthreads();
    int wave = t >> 6, lane = t & 63;
    int n = grp * 4 + wave;
    double cx = (double)xs[n], cy = (double)ys[n], cz = (double)zs[n];
    double sqn = -((cx * cx + cy * cy) + cz * cz);
    double val[32];
#pragma unroll
    for (int j = 0; j < 32; j++) {
        int cand = j * 64 + lane;             // stride-64: conflict-free LDS reads
        double mx = (double)xs[cand], my = (double)ys[cand], mz = (double)zs[cand];
        double dot = (cx * mx + cy * my) + cz * mz;
        double sqm = -((mx * mx + my * my) + mz * mz);
        val[j] = (sqn + 2.0 * dot) + sqm;
    }
    unsigned mask = 0xFFFFFFFFu;
    int myout = 0;
    for (int r = 0; r < 32; r++) {
        double bv = -1.0e300; int bj = 0;
#pragma unroll
        for (int j = 0; j < 32; j++) {
            if (((mask >> j) & 1u) && val[j] > bv) { bv = val[j]; bj = j; }
        }
        unsigned gi = (unsigned)(bj * 64 + lane);
        if (!mask) gi = 0xFFFFFFFFu;          // lane exhausted (can't win)
#pragma unroll
        for (int off = 32; off >= 1; off >>= 1) {
            double obv = __shfl_xor(bv, off);
            unsigned ogi = __shfl_xor(gi, off);
            if (obv > bv || (obv == bv && ogi < gi)) { bv = obv; gi = ogi; }
        }
        if ((gi & 63u) == (unsigned)lane) mask &= ~(1u << (gi >> 6));
        if (lane == r) myout = (int)gi;
    }
    if (lane < 32) idxout[((size_t)b * NPTS + n) * KNB + lane] = myout;
}

// ---------------- feature transpose [B,64,N] -> [B,N,64] -------------------
__global__ __launch_bounds__(256) void transpose_kernel(const float* __restrict__ feat,
                                                        float* __restrict__ fT) {
    __shared__ float tile[64][65];
    int b = blockIdx.x / (NPTS / 64);
    int n0 = (blockIdx.x % (NPTS / 64)) * 64;
    int t = threadIdx.x;
    int nt = t % 64, cg = t / 64;
    for (int cc = 0; cc < 16; cc++) {
        int c = cg * 16 + cc;
        tile[c][nt] = feat[((size_t)b * 64 + c) * NPTS + n0 + nt];
    }
    __syncthreads();
    int c = t % 64, ng = t / 64;
    for (int nn2 = 0; nn2 < 16; nn2++) {
        int n = ng * 16 + nn2;
        fT[((size_t)b * NPTS + n0 + n) * 64 + c] = tile[c][n];
    }
}

// ----- conv weight: fold group-shuffle + transpose -> wT2[i=f*32+col][o] ---
__global__ __launch_bounds__(256) void wprep_kernel(const float* __restrict__ cw,
                                                    float* __restrict__ wT2) {
    int gid = blockIdx.x * 256 + threadIdx.x;
    if (gid >= KCONV * OUTC) return;
    int i = gid / 64, o = gid % 64;
    int f = i / 32, col = i % 32;
    int fnew = (f % 24) * 4 + f / 24;   // shuffled position of original channel f
    wT2[(size_t)i * 64 + o] = cw[(size_t)o * KCONV + fnew * 32 + col];
}

// ---------------- per-point kernel: geometry, MLP, perm, of ---------------
__global__ __launch_bounds__(256) void point_kernel(
    const float* __restrict__ x, const float* __restrict__ fT,
    const int* __restrict__ idx, const float* __restrict__ Bm,
    const float* __restrict__ ker, const float* __restrict__ mw,
    const float* __restrict__ mb, unsigned short* __restrict__ Aof,
    int m_base, int m_count) {
    __shared__ float B_l[224];
    __shared__ float K_l[96];
    __shared__ float MWI[2048];
    __shared__ float MB[32];
    __shared__ double U[4][1536];   // per-wave union: pmd[32][33] dbl | fsf[96][32] f32
    int t = threadIdx.x;
    for (int i = t; i < 224; i += 256) B_l[i] = Bm[i];
    for (int i = t; i < 96; i += 256) K_l[i] = ker[i];
    for (int i = t; i < 2048; i += 256) {
        int o = i / 64, jj = i % 64;
        int dst = (jj < 32) ? (o * 64 + 2 * jj) : (o * 64 + 2 * (jj - 32) + 1);
        MWI[dst] = mw[i];
    }
    for (int i = t; i < 32; i += 256) MB[i] = mb[i];
    __syncthreads();

    int wv = t >> 6, lane = t & 63;
    int k = lane & 31, h = lane >> 5;
    double* pmd = U[wv];
    float* fsf = (float*)U[wv];
    int gw = blockIdx.x * 4 + wv;
    int nw = gridDim.x * 4;

    for (int mi = gw; mi < m_count; mi += nw) {
        int m = m_base + mi;
        int b = m >> 11;
        int ik = idx[(size_t)m * KNB + k];
        const float* xb = x + (size_t)b * 3 * NPTS;
        float nx0 = xb[ik], ny0 = xb[NPTS + ik], nz0 = xb[2 * NPTS + ik];
        float cx = __shfl(nx0, 0), cy = __shfl(ny0, 0), cz = __shfl(nz0, 0);
        double rxd = (double)nx0 - (double)cx;
        double ryd = (double)ny0 - (double)cy;
        double rzd = (double)nz0 - (double)cz;
        float rx = (float)rxd, ry = (float)ryd, rz = (float)rzd;
        float dist = sqrtf((rx * rx + ry * ry) + rz * rz);

        // phase 2: p[k][col] in fp64 (tie-exact vs np reference)
#pragma unroll
        for (int cc = 0; cc < 16; cc++) {
            int col = h * 16 + cc;
            double v = rxd * (double)K_l[col]
                     + ryd * (double)K_l[32 + col]
                     + rzd * (double)K_l[64 + col];
            if (k == 0 && col == 0) v += 1.0;
            pmd[k * 33 + col] = v;
        }
        asm volatile("" ::: "memory");

        // phase 3: fp64 top-3 threshold, fp32 softmax (col = k, both halves dup)
        int col = k;
        double m1 = -1.0e300, m2 = -1.0e300, m3 = -1.0e300;
#pragma unroll
        for (int kk = 0; kk < 32; kk++) {
            double v = pmd[kk * 33 + col];
            if (v > m1) { m3 = m2; m2 = m1; m1 = v; }
            else if (v > m2) { m3 = m2; m2 = v; }
            else if (v > m3) { m3 = v; }
        }
        float pv[32];
        float ssum = 0.0f;
#pragma unroll
        for (int kk = 0; kk < 32; kk++) {
            double v = pmd[kk * 33 + col];
            float e = (v >= m3) ? __expf((float)(v - m1)) : 0.0f;
            pv[kk] = e; ssum += e;
        }
        float rs = 1.0f / ssum;
#pragma unroll
        for (int kk = 0; kk < 32; kk++) pv[kk] *= rs;
        asm volatile("" ::: "memory");

        // phase 4: Fourier features + MLP -> x_feats[o][k]
        float xf[32];
#pragma unroll
        for (int o = 0; o < 32; o++) xf[o] = 0.0f;
#pragma unroll
        for (int jp = 0; jp < 8; jp++) {
            int j0 = h * 16 + jp * 2;
            float u0 = cx * B_l[j0];
            u0 = fmaf(cy, B_l[32 + j0], u0);
            u0 = fmaf(cz, B_l[64 + j0], u0);
            u0 = fmaf(rx, B_l[96 + j0], u0);
            u0 = fmaf(ry, B_l[128 + j0], u0);
            u0 = fmaf(rz, B_l[160 + j0], u0);
            u0 = fmaf(dist, B_l[192 + j0], u0);
            float ff0 = 6.28318530717958647692f * u0;
            int j1 = j0 + 1;
            float u1 = cx * B_l[j1];
            u1 = fmaf(cy, B_l[32 + j1], u1);
            u1 = fmaf(cz, B_l[64 + j1], u1);
            u1 = fmaf(rx, B_l[96 + j1], u1);
            u1 = fmaf(ry, B_l[128 + j1], u1);
            u1 = fmaf(rz, B_l[160 + j1], u1);
            u1 = fmaf(dist, B_l[192 + j1], u1);
            float ff1 = 6.28318530717958647692f * u1;
            float s0 = __sinf(ff0), c0n = __cosf(ff0);
            float s1 = __sinf(ff1), c1n = __cosf(ff1);
#pragma unroll
            for (int o = 0; o < 32; o++) {
                float4 w4 = *(const float4*)&MWI[o * 64 + 2 * j0];
                float a = xf[o];
                a = fmaf(s0, w4.x, a);
                a = fmaf(c0n, w4.y, a);
                a = fmaf(s1, w4.z, a);
                a = fmaf(c1n, w4.w, a);
                xf[o] = a;
            }
        }
#pragma unroll
        for (int o = 0; o < 32; o++) xf[o] += __shfl_xor(xf[o], 32);
#pragma unroll
        for (int oo = 0; oo < 16; oo++) {
            int o = h * 16 + oo;
            fsf[(64 + o) * 32 + k] = xf[o] + MB[o];
        }
        // phase 5: gather neighbor features rows 0..63 (fp32)
        const float* fr = fT + ((size_t)b * NPTS + ik) * 64;
#pragma unroll
        for (int q = 0; q < 8; q++) {
            int c0 = h * 32 + q * 4;
            float4 v4 = *(const float4*)&fr[c0];
            fsf[(c0 + 0) * 32 + k] = v4.x;
            fsf[(c0 + 1) * 32 + k] = v4.y;
            fsf[(c0 + 2) * 32 + k] = v4.z;
            fsf[(c0 + 3) * 32 + k] = v4.w;
        }
        asm volatile("" ::: "memory");

        // phase 6: of[f][col] = sum_k fsf[f][k] * pv[k]
#pragma unroll 2
        for (int fp = 0; fp < 48; fp++) {
            int f = fp * 2 + h;
            float acc = 0.0f;
#pragma unroll
            for (int q = 0; q < 8; q++) {
                float4 a4 = *(const float4*)&fsf[f * 32 + q * 4];
                acc = fmaf(a4.x, pv[q * 4 + 0], acc);
                acc = fmaf(a4.y, pv[q * 4 + 1], acc);
                acc = fmaf(a4.z, pv[q * 4 + 2], acc);
                acc = fmaf(a4.w, pv[q * 4 + 3], acc);
            }
            Aof[(size_t)mi * KCONV + f * 32 + col] = f2bf(acc);
        }
        asm volatile("" ::: "memory");
    }
}

// ---------------- conv GEMM: out[m][o] += A[m][:] . wT2[:][o] -------------
__global__ __launch_bounds__(256) void conv_kernel(
    const unsigned short* __restrict__ A, const float* __restrict__ W,
    const float* __restrict__ bias, float* __restrict__ outp,
    int m_base, int m_count, int KS) {
    __shared__ float Al[32 * 68];
    __shared__ float Wl[64 * 68];
    int nmb = m_count / 32;
    int bm = blockIdx.x % nmb, ks = blockIdx.x / nmb;
    int m0 = bm * 32;
    int KL = KCONV / KS;
    int k0base = ks * KL;
    int t = threadIdx.x;
    float acc[4][2] = {};
    int mh = t % 8, og = t / 8;
    for (int kt = 0; kt < KL; kt += 64) {
        int k0 = k0base + kt;
        {
            int mr = t / 8, kq = t % 8;
            const unsigned short* ap = A + (size_t)(m0 + mr) * KCONV + k0 + kq * 8;
            uint4 u = *(const uint4*)ap;
            float4 lo4 = make_float4(bflo(u.x), bfhi(u.x), bflo(u.y), bfhi(u.y));
            float4 hi4 = make_float4(bflo(u.z), bfhi(u.z), bflo(u.w), bfhi(u.w));
            *(float4*)&Al[mr * 68 + kq * 8] = lo4;
            *(float4*)&Al[mr * 68 + kq * 8 + 4] = hi4;
        }
#pragma unroll
        for (int r4 = 0; r4 < 16; r4++) {
            int row = r4 * 4 + t / 64;
            Wl[(t % 64) * 68 + row] = W[(size_t)(k0 + row) * 64 + (t % 64)];
        }
        __syncthreads();
#pragma unroll
        for (int q = 0; q < 16; q++) {
            float4 a0 = *(const float4*)&Al[mh * 68 + q * 4];
            float4 a1 = *(const float4*)&Al[(mh + 8) * 68 + q * 4];
            float4 a2 = *(const float4*)&Al[(mh + 16) * 68 + q * 4];
            float4 a3 = *(const float4*)&Al[(mh + 24) * 68 + q * 4];
            float4 w0 = *(const float4*)&Wl[(2 * og) * 68 + q * 4];
            float4 w1 = *(const float4*)&Wl[(2 * og + 1) * 68 + q * 4];
            acc[0][0] = fmaf(a0.x, w0.x, acc[0][0]); acc[0][0] = fmaf(a0.y, w0.y, acc[0][0]);
            acc[0][0] = fmaf(a0.z, w0.z, acc[0][0]); acc[0][0] = fmaf(a0.w, w0.w, acc[0][0]);
            acc[0][1] = fmaf(a0.x, w1.x, acc[0][1]); acc[0][1] = fmaf(a0.y, w1.y, acc[0][1]);
            acc[0][1] = fmaf(a0.z, w1.z, acc[0][1]); acc[0][1] = fmaf(a0.w, w1.w, acc[0][1]);
            acc[1][0] = fmaf(a1.x, w0.x, acc[1][0]); acc[1][0] = fmaf(a1.y, w0.y, acc[1][0]);
            acc[1][0] = fmaf(a1.z, w0.z, acc[1][0]); acc[1][0] = fmaf(a1.w, w0.w, acc[1][0]);
            acc[1][1] = fmaf(a1.x, w1.x, acc[1][1]); acc[1][1] = fmaf(a1.y, w1.y, acc[1][1]);
            acc[1][1] = fmaf(a1.z, w1.z, acc[1][1]); acc[1][1] = fmaf(a1.w, w1.w, acc[1][1]);
            acc[2][0] = fmaf(a2.x, w0.x, acc[2][0]); acc[2][0] = fmaf(a2.y, w0.y, acc[2][0]);
            acc[2][0] = fmaf(a2.z, w0.z, acc[2][0]); acc[2][0] = fmaf(a2.w, w0.w, acc[2][0]);
            acc[2][1] = fmaf(a2.x, w1.x, acc[2][1]); acc[2][1] = fmaf(a2.y, w1.y, acc[2][1]);
            acc[2][1] = fmaf(a2.z, w1.z, acc[2][1]); acc[2][1] = fmaf(a2.w, w1.w, acc[2][1]);
            acc[3][0] = fmaf(a3.x, w0.x, acc[3][0]); acc[3][0] = fmaf(a3.y, w0.y, acc[3][0]);
            acc[3][0] = fmaf(a3.z, w0.z, acc[3][0]); acc[3][0] = fmaf(a3.w, w0.w, acc[3][0]);
            acc[3][1] = fmaf(a3.x, w1.x, acc[3][1]); acc[3][1] = fmaf(a3.y, w1.y, acc[3][1]);
            acc[3][1] = fmaf(a3.z, w1.z, acc[3][1]); acc[3][1] = fmaf(a3.w, w1.w, acc[3][1]);
        }
        __syncthreads();
    }
#pragma unroll
    for (int r = 0; r < 4; r++) {
        int m = m_base + m0 + mh + r * 8;
        int b = m >> 11, n = m & 2047;
#pragma unroll
        for (int oo = 0; oo < 2; oo++) {
            int o = 2 * og + oo;
            float v = acc[r][oo];
            if (ks == 0) v += bias[o];
            atomicAdd(&outp[((size_t)b * 64 + o) * NPTS + n], v);
        }
    }
}

// ---------------- BatchNorm -----------------------------------------------
__global__ __launch_bounds__(256) void bn1_kernel(const float* __restrict__ outp,
                                                  float* __restrict__ sums) {
    int c = blockIdx.x, t = threadIdx.x;
    float s = 0.0f, s2 = 0.0f;
    for (int b = 0; b < NBATCH; b++) {
        const float* p = outp + ((size_t)b * 64 + c) * NPTS;
        for (int i = t; i < NPTS; i += 256) {
            float v = p[i];
            s += v; s2 = fmaf(v, v, s2);
        }
    }
    __shared__ float r1[256], r2[256];
    r1[t] = s; r2[t] = s2;
    __syncthreads();
    for (int st = 128; st > 0; st >>= 1) {
        if (t < st) { r1[t] += r1[t + st]; r2[t] += r2[t + st]; }
        __syncthreads();
    }
    if (t == 0) { sums[c] = r1[0]; sums[64 + c] = r2[0]; }
}

__global__ __launch_bounds__(256) void bn2_kernel(float* __restrict__ outp,
                                                  const float* __restrict__ sums,
                                                  const float* __restrict__ gamma,
                                                  const float* __restrict__ beta) {
    int i = blockIdx.x * 256 + threadIdx.x;
    if (i >= MTOT * 64) return;
    int c = (i >> 11) & 63;
    float mean = sums[c] * (1.0f / (float)MTOT);
    float var = sums[64 + c] * (1.0f / (float)MTOT) - mean * mean;
    float inv = rsqrtf(var + 1e-5f);
    outp[i] = fmaf(gamma[c], (outp[i] - mean) * inv, beta[c]);
}

extern "C" void kernel_launch(void* const* d_in, const int* in_sizes, int n_in,
                              void* d_out, int out_size, void* d_ws, size_t ws_size,
                              hipStream_t stream) {
    (void)in_sizes; (void)n_in;
    const float* x   = (const float*)d_in[0];
    const float* fea = (const float*)d_in[1];
    const float* Bm  = (const float*)d_in[2];
    const float* ker = (const float*)d_in[3];
    const float* mw  = (const float*)d_in[4];
    const float* mb  = (const float*)d_in[5];
    const float* cw  = (const float*)d_in[6];
    const float* cb  = (const float*)d_in[7];
    const float* gam = (const float*)d_in[8];
    const float* bet = (const float*)d_in[9];
    float* outp = (float*)d_out;

    char* wsb = (char*)d_ws;
    size_t off = 0;
    auto carve = [&](size_t sz) {
        void* p = wsb + off;
        off = (off + sz + 255) & ~(size_t)255;
        return p;
    };
    float* fT   = (float*)carve((size_t)MTOT * 64 * 4);
    int*   idxw = (int*)carve((size_t)MTOT * KNB * 4);
    float* wT2  = (float*)carve((size_t)KCONV * 64 * 4);
    float* sums = (float*)carve(2 * 64 * 4);
    size_t fixedEnd = off;
    int CS = 16384;
    if (fixedEnd + (size_t)16384 * KCONV * 2 > ws_size) CS = 4096;
    if (fixedEnd + (size_t)CS * KCONV * 2 > ws_size) CS = 1024;
    unsigned short* Aof = (unsigned short*)(wsb + fixedEnd);
    int KS = (CS == 16384) ? 1 : ((CS == 4096) ? 4 : 16);
    int grid1 = (CS >= 2048) ? 512 : 256;

    hipMemsetAsync(d_out, 0, (size_t)out_size * sizeof(float), stream);
    hipMemsetAsync(sums, 0, 2 * 64 * 4, stream);

    knn_kernel<<<NBATCH * (NPTS / 4), 256, 0, stream>>>(x, idxw);
    transpose_kernel<<<NBATCH * (NPTS / 64), 256, 0, stream>>>(fea, fT);
    wprep_kernel<<<(KCONV * OUTC + 255) / 256, 256, 0, stream>>>(cw, wT2);

    for (int c0 = 0; c0 < MTOT; c0 += CS) {
        point_kernel<<<grid1, 256, 0, stream>>>(x, fT, idxw, Bm, ker, mw, mb,
                                                Aof, c0, CS);
        conv_kernel<<<(CS / 32) * KS, 256, 0, stream>>>(Aof, wT2, cb, outp,
                                                        c0, CS, KS);
    }
    bn1_kernel<<<64, 256, 0, stream>>>(outp, sums);
    bn2_kernel<<<(MTOT * 64 + 255) / 256, 256, 0, stream>>>(outp, sums, gam, bet);
}

// Round 3
// 418.249 us; speedup vs baseline: 1.9698x; 1.9698x over previous
//
#include <hip/hip_runtime.h>
#include <math.h>

#define NPTS 2048
#define NBATCH 8
#define MTOT (NBATCH*NPTS)
#define KROW 4096   // conv K: 128 rows * 32 cols
#define OUTC 64

using bf16x8 = __attribute__((ext_vector_type(8))) short;
using f32x4  = __attribute__((ext_vector_type(4))) float;

__device__ __forceinline__ unsigned short f2bf(float f) {
    unsigned u = __float_as_uint(f);
    unsigned r = u + 0x7FFFu + ((u >> 16) & 1u);
    return (unsigned short)(r >> 16);
}

// ---- KNN: top-32 by fp64 pair value (desc), index asc tie-break (UNCHANGED)
__global__ __launch_bounds__(256) void knn_kernel(const float* __restrict__ x,
                                                  int* __restrict__ idxout) {
    __shared__ float xs[NPTS], ys[NPTS], zs[NPTS];
    int t = threadIdx.x;
    int b = blockIdx.x / (NPTS / 4);
    int grp = blockIdx.x % (NPTS / 4);
    const float* xb = x + (size_t)b * 3 * NPTS;
    for (int i = t; i < NPTS; i += 256) {
        xs[i] = xb[i]; ys[i] = xb[NPTS + i]; zs[i] = xb[2 * NPTS + i];
    }
    __syncthreads();
    int wave = t >> 6, lane = t & 63;
    int n = grp * 4 + wave;
    double cx = (double)xs[n], cy = (double)ys[n], cz = (double)zs[n];
    double sqn = -((cx * cx + cy * cy) + cz * cz);
    double val[32];
#pragma unroll
    for (int j = 0; j < 32; j++) {
        int cand = j * 64 + lane;
        double mx = (double)xs[cand], my = (double)ys[cand], mz = (double)zs[cand];
        double dot = (cx * mx + cy * my) + cz * mz;
        double sqm = -((mx * mx + my * my) + mz * mz);
        val[j] = (sqn + 2.0 * dot) + sqm;
    }
    unsigned mask = 0xFFFFFFFFu;
    int myout = 0;
    for (int r = 0; r < 32; r++) {
        double bv = -1.0e300; int bj = 0;
#pragma unroll
        for (int j = 0; j < 32; j++) {
            if (((mask >> j) & 1u) && val[j] > bv) { bv = val[j]; bj = j; }
        }
        unsigned gi = (unsigned)(bj * 64 + lane);
        if (!mask) gi = 0xFFFFFFFFu;
#pragma unroll
        for (int off = 32; off >= 1; off >>= 1) {
            double obv = __shfl_xor(bv, off);
            unsigned ogi = __shfl_xor(gi, off);
            if (obv > bv || (obv == bv && ogi < gi)) { bv = obv; gi = ogi; }
        }
        if ((gi & 63u) == (unsigned)lane) mask &= ~(1u << (gi >> 6));
        if (lane == r) myout = (int)gi;
    }
    if (lane < 32) idxout[((size_t)b * NPTS + n) * 32 + lane] = myout;
}

// ---------------- feature transpose [B,64,N] -> bf16 [B,N,64] --------------
__global__ __launch_bounds__(256) void transpose_kernel(const float* __restrict__ feat,
                                                        unsigned short* __restrict__ fTb) {
    __shared__ float tile[64][65];
    int b = blockIdx.x / 32;
    int n0 = (blockIdx.x % 32) * 64;
    int t = threadIdx.x;
    int nt = t % 64, cg = t / 64;
    for (int cc = 0; cc < 16; cc++) {
        int c2 = cg * 16 + cc;
        tile[c2][nt] = feat[((size_t)b * 64 + c2) * NPTS + n0 + nt];
    }
    __syncthreads();
    int c2 = t % 64, ng = t / 64;
    for (int nn2 = 0; nn2 < 16; nn2++) {
        int n = ng * 16 + nn2;
        fTb[((size_t)b * NPTS + n0 + n) * 64 + c2] = f2bf(tile[c2][n]);
    }
}

// ---- weight prep: fold group-shuffle + MLP into WtT[oc][4096] bf16 --------
__global__ __launch_bounds__(256) void wprep2_kernel(
    const float* __restrict__ cw, const float* __restrict__ mlpw,
    const float* __restrict__ mb, const float* __restrict__ cb,
    unsigned short* __restrict__ WtT, float* __restrict__ cbw) {
    int oc = blockIdx.x;
    int t = threadIdx.x;
    for (int i = t; i < 2048; i += 256) {
        int f = i >> 5, col = i & 31;
        int r = (f % 24) * 4 + f / 24;
        WtT[(size_t)oc * KROW + i] = f2bf(cw[(size_t)oc * 3072 + r * 32 + col]);
    }
    for (int i = t; i < 2048; i += 256) {
        int j = i >> 5, col = i & 31;
        float s = 0.f;
        for (int o2 = 0; o2 < 32; o2++) {
            int f = 64 + o2;
            int r = (f % 24) * 4 + f / 24;
            s = fmaf(mlpw[o2 * 64 + j], cw[(size_t)oc * 3072 + r * 32 + col], s);
        }
        WtT[(size_t)oc * KROW + 2048 + i] = f2bf(s);
    }
    if (t == 0) {
        float s = cb[oc];
        for (int o2 = 0; o2 < 32; o2++) {
            int f = 64 + o2;
            int r = (f % 24) * 4 + f / 24;
            float rowsum = 0.f;
            for (int col = 0; col < 32; col++) rowsum += cw[(size_t)oc * 3072 + r * 32 + col];
            s = fmaf(mb[o2], rowsum, s);
        }
        cbw[oc] = s;
    }
}

__global__ void kprep_kernel(const float* __restrict__ ker, double* __restrict__ kerd) {
    int i = threadIdx.x;
    if (i < 96) kerd[i] = (double)ker[i];
}

// ---------------- per-point kernel: geometry, perm, G, O=G*perm (MFMA) -----
__global__ __launch_bounds__(256) void point2_kernel(
    const float* __restrict__ x, const unsigned short* __restrict__ fTb,
    const int* __restrict__ idx, const float* __restrict__ Bm,
    const double* __restrict__ kerd, unsigned short* __restrict__ Aof,
    int m_base, int m_count) {
    __shared__ double ldsbuf[4 * 1600];   // 4 waves * 12800 B
    int t = threadIdx.x;
    int wv = t >> 6, l = t & 63;
    int k = l & 31, h = l >> 5;
    char* base = (char*)ldsbuf + wv * 12800;
    double* pmd = (double*)base;                       // [32][33] f64 (8448 B)
    unsigned short* G = (unsigned short*)base;         // [128][40] bf16 (10240 B)
    unsigned short* PT = (unsigned short*)(base + 10240); // [32][40] bf16
    int lr = l & 15, lq = l >> 4;
    int gw = blockIdx.x * 4 + wv;
    int nw = gridDim.x * 4;

    for (int mi = gw; mi < m_count; mi += nw) {
        int m = m_base + mi;
        int b = m >> 11;
        int ik = idx[(size_t)m * 32 + k];
        const float* xb = x + (size_t)b * 3 * NPTS;
        float nx0 = xb[ik], ny0 = xb[NPTS + ik], nz0 = xb[2 * NPTS + ik];
        float cx = __shfl(nx0, 0), cy = __shfl(ny0, 0), cz = __shfl(nz0, 0);
        double rxd = (double)nx0 - (double)cx;
        double ryd = (double)ny0 - (double)cy;
        double rzd = (double)nz0 - (double)cz;
        float rx = (float)rxd, ry = (float)ryd, rz = (float)rzd;
        float dist = sqrtf((rx * rx + ry * ry) + rz * rz);

        // phase 2: p[k][c] fp64 (SGPR kernels), write own half
        double vd[32];
#pragma unroll
        for (int c = 0; c < 32; c++) {
            double v = rxd * kerd[c] + ryd * kerd[32 + c] + rzd * kerd[64 + c];
            if (k == 0 && c == 0) v += 1.0;
            vd[c] = v;
        }
#pragma unroll
        for (int cc = 0; cc < 16; cc++) {
            double vv = h ? vd[cc + 16] : vd[cc];
            pmd[k * 33 + h * 16 + cc] = vv;
        }
        asm volatile("" ::: "memory");

        // phase 3: fp64 top-3 threshold, fp32 softmax; column c = k
        int c = k;
        double pvd[32];
#pragma unroll
        for (int kk = 0; kk < 32; kk++) pvd[kk] = pmd[kk * 33 + c];
        double m1 = -1.0e300, m2 = -1.0e300, m3 = -1.0e300;
#pragma unroll
        for (int kk = 0; kk < 32; kk++) {
            double v = pvd[kk];
            if (v > m1) { m3 = m2; m2 = m1; m1 = v; }
            else if (v > m2) { m3 = m2; m2 = v; }
            else if (v > m3) { m3 = v; }
        }
        float pv[32];
        float ssum = 0.f;
#pragma unroll
        for (int kk = 0; kk < 32; kk++) {
            float e = (pvd[kk] >= m3) ? __expf((float)(pvd[kk] - m1)) : 0.f;
            pv[kk] = e; ssum += e;
        }
        float rs = 1.f / ssum;
#pragma unroll
        for (int kk = 0; kk < 32; kk++) pv[kk] *= rs;

        // permT row c (k-contiguous bf16); h=0 writes k 0..15, h=1 k 16..31
        unsigned w[16];
#pragma unroll
        for (int i = 0; i < 16; i++)
            w[i] = (unsigned)f2bf(pv[2 * i]) | ((unsigned)f2bf(pv[2 * i + 1]) << 16);
        unsigned s[8];
#pragma unroll
        for (int i = 0; i < 8; i++) s[i] = h ? w[8 + i] : w[i];
        *(uint4*)&PT[c * 40 + h * 16]     = make_uint4(s[0], s[1], s[2], s[3]);
        *(uint4*)&PT[c * 40 + h * 16 + 8] = make_uint4(s[4], s[5], s[6], s[7]);
        asm volatile("" ::: "memory");

        // G rows 0..63: gathered neighbor features (bf16), pair-pack across k
        {
            const unsigned short* fr = fTb + (((size_t)b * NPTS + ik) * 64 + h * 32);
            uint4 f0 = *(const uint4*)fr;
            uint4 f1 = *(const uint4*)(fr + 8);
            uint4 f2 = *(const uint4*)(fr + 16);
            uint4 f3 = *(const uint4*)(fr + 24);
            unsigned fw[16] = {f0.x, f0.y, f0.z, f0.w, f1.x, f1.y, f1.z, f1.w,
                               f2.x, f2.y, f2.z, f2.w, f3.x, f3.y, f3.z, f3.w};
#pragma unroll
            for (int c2 = 0; c2 < 16; c2++) {
                unsigned v = fw[c2];
                unsigned o = (unsigned)__shfl_xor((int)v, 1);
                unsigned wA = (k & 1) ? ((o & 0xFFFFu) | (v << 16)) : ((v & 0xFFFFu) | (o << 16));
                unsigned wB = (k & 1) ? ((o >> 16) | (v & 0xFFFF0000u)) : ((v >> 16) | (o & 0xFFFF0000u));
                int ch = h * 32 + 2 * c2 + (k & 1);
                unsigned wr = (k & 1) ? wB : wA;
                *(unsigned*)&G[ch * 40 + (k & ~1)] = wr;
            }
        }
        // G rows 64..127: Fourier features (SGPR B_mat, sin rows then cos rows)
        {
            float u[32];
#pragma unroll
            for (int f = 0; f < 32; f++) {
                float uu = cx * Bm[f];
                uu = fmaf(cy, Bm[32 + f], uu);
                uu = fmaf(cz, Bm[64 + f], uu);
                uu = fmaf(rx, Bm[96 + f], uu);
                uu = fmaf(ry, Bm[128 + f], uu);
                uu = fmaf(rz, Bm[160 + f], uu);
                uu = fmaf(dist, Bm[192 + f], uu);
                u[f] = 6.28318530717958647692f * uu;
            }
            float tv[32];
            if (h == 0) {
#pragma unroll
                for (int f = 0; f < 32; f++) tv[f] = __sinf(u[f]);
            } else {
#pragma unroll
                for (int f = 0; f < 32; f++) tv[f] = __cosf(u[f]);
            }
#pragma unroll
            for (int jj = 0; jj < 16; jj++) {
                unsigned b0 = f2bf(tv[jj]), b1 = f2bf(tv[jj + 16]);
                unsigned o0 = (unsigned)__shfl_xor((int)b0, 1);
                unsigned o1 = (unsigned)__shfl_xor((int)b1, 1);
                unsigned wr = (k & 1) ? ((o1 & 0xFFFFu) | (b1 << 16))
                                      : ((b0 & 0xFFFFu) | (o0 << 16));
                int ch = 64 + h * 32 + (k & 1) * 16 + jj;
                *(unsigned*)&G[ch * 40 + (k & ~1)] = wr;
            }
        }
        asm volatile("" ::: "memory");

        // O^T = perm^T * G^T via MFMA; store O[f][c] bf16 to Aof
        bf16x8 af0 = *(const bf16x8*)&PT[(lr)      * 40 + lq * 8];
        bf16x8 af1 = *(const bf16x8*)&PT[(16 + lr) * 40 + lq * 8];
        size_t obase = (size_t)mi * KROW;
#pragma unroll
        for (int fb = 0; fb < 8; fb++) {
            bf16x8 bfr = *(const bf16x8*)&G[(fb * 16 + lr) * 40 + lq * 8];
            f32x4 d0 = __builtin_amdgcn_mfma_f32_16x16x32_bf16(af0, bfr, (f32x4){0.f, 0.f, 0.f, 0.f}, 0, 0, 0);
            f32x4 d1 = __builtin_amdgcn_mfma_f32_16x16x32_bf16(af1, bfr, (f32x4){0.f, 0.f, 0.f, 0.f}, 0, 0, 0);
            int f = fb * 16 + lr;
            unsigned q0 = (unsigned)f2bf(d0.x) | ((unsigned)f2bf(d0.y) << 16);
            unsigned q1 = (unsigned)f2bf(d0.z) | ((unsigned)f2bf(d0.w) << 16);
            *(uint2*)&Aof[obase + f * 32 + lq * 4] = make_uint2(q0, q1);
            unsigned q2 = (unsigned)f2bf(d1.x) | ((unsigned)f2bf(d1.y) << 16);
            unsigned q3 = (unsigned)f2bf(d1.z) | ((unsigned)f2bf(d1.w) << 16);
            *(uint2*)&Aof[obase + f * 32 + 16 + lq * 4] = make_uint2(q2, q3);
        }
        asm volatile("" ::: "memory");
    }
}

// ---------------- conv GEMM (MFMA): out = Aof[CSx4096] * Wtot --------------
__global__ __launch_bounds__(256) void conv2_kernel(
    const unsigned short* __restrict__ A, const unsigned short* __restrict__ WtT,
    const float* __restrict__ cbw, float* __restrict__ outp, int m_base) {
    __shared__ unsigned short Al[64 * 72];
    __shared__ unsigned short Wl[64 * 72];
    int t = threadIdx.x;
    int wv = t >> 6, l = t & 63;
    int lr = l & 15, lq = l >> 4;
    int m0 = blockIdx.x * 64;
    int mr = t >> 3, kq = t & 7;
    f32x4 acc[4] = {};
    for (int ks = 0; ks < 64; ks++) {
        int k0 = ks * 64;
        uint4 a0 = *(const uint4*)&A[(size_t)(m0 + mr) * KROW + k0 + kq * 8];
        uint4 a1 = *(const uint4*)&A[(size_t)(m0 + mr + 32) * KROW + k0 + kq * 8];
        uint4 w0 = *(const uint4*)&WtT[(size_t)mr * KROW + k0 + kq * 8];
        uint4 w1 = *(const uint4*)&WtT[(size_t)(mr + 32) * KROW + k0 + kq * 8];
        __syncthreads();
        *(uint4*)&Al[mr * 72 + kq * 8] = a0;
        *(uint4*)&Al[(mr + 32) * 72 + kq * 8] = a1;
        *(uint4*)&Wl[mr * 72 + kq * 8] = w0;
        *(uint4*)&Wl[(mr + 32) * 72 + kq * 8] = w1;
        __syncthreads();
#pragma unroll
        for (int kk = 0; kk < 2; kk++) {
            bf16x8 af = *(const bf16x8*)&Al[(wv * 16 + lr) * 72 + kk * 32 + lq * 8];
#pragma unroll
            for (int ocb = 0; ocb < 4; ocb++) {
                bf16x8 wf = *(const bf16x8*)&Wl[(ocb * 16 + lr) * 72 + kk * 32 + lq * 8];
                acc[ocb] = __builtin_amdgcn_mfma_f32_16x16x32_bf16(af, wf, acc[ocb], 0, 0, 0);
            }
        }
    }
    int m = m_base + m0 + wv * 16 + lq * 4;
    int b = m >> 11, n = m & 2047;
#pragma unroll
    for (int ocb = 0; ocb < 4; ocb++) {
        int oc = ocb * 16 + lr;
        float bias = cbw[oc];
        float4 v = make_float4(acc[ocb].x + bias, acc[ocb].y + bias,
                               acc[ocb].z + bias, acc[ocb].w + bias);
        *(float4*)&outp[((size_t)(b * 64 + oc)) * 2048 + n] = v;
    }
}

// ---------------- BatchNorm -----------------------------------------------
__global__ __launch_bounds__(256) void bn1_kernel(const float* __restrict__ outp,
                                                  float* __restrict__ sums) {
    int c = blockIdx.x, t = threadIdx.x;
    float s = 0.0f, s2 = 0.0f;
    for (int b = 0; b < NBATCH; b++) {
        const float* p = outp + ((size_t)b * 64 + c) * NPTS;
        for (int i = t; i < NPTS; i += 256) {
            float v = p[i];
            s += v; s2 = fmaf(v, v, s2);
        }
    }
    __shared__ float r1[256], r2[256];
    r1[t] = s; r2[t] = s2;
    __syncthreads();
    for (int st = 128; st > 0; st >>= 1) {
        if (t < st) { r1[t] += r1[t + st]; r2[t] += r2[t + st]; }
        __syncthreads();
    }
    if (t == 0) { sums[c] = r1[0]; sums[64 + c] = r2[0]; }
}

__global__ __launch_bounds__(256) void bn2_kernel(float* __restrict__ outp,
                                                  const float* __restrict__ sums,
                                                  const float* __restrict__ gamma,
                                                  const float* __restrict__ beta) {
    int i = blockIdx.x * 256 + threadIdx.x;
    if (i >= MTOT * 64) return;
    int c = (i >> 11) & 63;
    float mean = sums[c] * (1.0f / (float)MTOT);
    float var = sums[64 + c] * (1.0f / (float)MTOT) - mean * mean;
    float inv = rsqrtf(var + 1e-5f);
    outp[i] = fmaf(gamma[c], (outp[i] - mean) * inv, beta[c]);
}

extern "C" void kernel_launch(void* const* d_in, const int* in_sizes, int n_in,
                              void* d_out, int out_size, void* d_ws, size_t ws_size,
                              hipStream_t stream) {
    (void)in_sizes; (void)n_in; (void)out_size;
    const float* x    = (const float*)d_in[0];
    const float* fea  = (const float*)d_in[1];
    const float* Bm   = (const float*)d_in[2];
    const float* ker  = (const float*)d_in[3];
    const float* mw   = (const float*)d_in[4];
    const float* mb   = (const float*)d_in[5];
    const float* cw   = (const float*)d_in[6];
    const float* cb   = (const float*)d_in[7];
    const float* gam  = (const float*)d_in[8];
    const float* bet  = (const float*)d_in[9];
    float* outp = (float*)d_out;

    char* wsb = (char*)d_ws;
    size_t off = 0;
    auto carve = [&](size_t sz) {
        void* p = wsb + off;
        off = (off + sz + 255) & ~(size_t)255;
        return p;
    };
    unsigned short* fTb  = (unsigned short*)carve((size_t)MTOT * 64 * 2);
    int*            idxw = (int*)carve((size_t)MTOT * 32 * 4);
    unsigned short* WtT  = (unsigned short*)carve((size_t)OUTC * KROW * 2);
    float*          cbw  = (float*)carve(64 * 4);
    double*         kerd = (double*)carve(96 * 8);
    float*          sums = (float*)carve(2 * 64 * 4);
    size_t fixedEnd = off;
    int CS = 16384;
    while (fixedEnd + (size_t)CS * KROW * 2 > ws_size && CS > 2048) CS >>= 1;
    unsigned short* Aof = (unsigned short*)(wsb + fixedEnd);

    knn_kernel<<<NBATCH * (NPTS / 4), 256, 0, stream>>>(x, idxw);
    transpose_kernel<<<NBATCH * 32, 256, 0, stream>>>(fea, fTb);
    wprep2_kernel<<<64, 256, 0, stream>>>(cw, mw, mb, cb, WtT, cbw);
    kprep_kernel<<<1, 128, 0, stream>>>(ker, kerd);

    for (int c0 = 0; c0 < MTOT; c0 += CS) {
        point2_kernel<<<768, 256, 0, stream>>>(x, fTb, idxw, Bm, kerd, Aof, c0, CS);
        conv2_kernel<<<CS / 64, 256, 0, stream>>>(Aof, WtT, cbw, outp, c0);
    }
    bn1_kernel<<<64, 256, 0, stream>>>(outp, sums);
    bn2_kernel<<<(MTOT * 64 + 255) / 256, 256, 0, stream>>>(outp, sums, gam, bet);
}

// Round 4
// 327.571 us; speedup vs baseline: 2.5151x; 1.2768x over previous
//
#include <hip/hip_runtime.h>
#include <math.h>

#define NPTS 2048
#define NBATCH 8
#define MTOT (NBATCH*NPTS)
#define KROW 4096   // conv K: 128 rows * 32 cols
#define OUTC 64

using bf16x8 = __attribute__((ext_vector_type(8))) short;
using f32x4  = __attribute__((ext_vector_type(4))) float;

__device__ __forceinline__ unsigned short f2bf(float f) {
    unsigned u = __float_as_uint(f);
    unsigned r = u + 0x7FFFu + ((u >> 16) & 1u);
    return (unsigned short)(r >> 16);
}

// ---- KNN: fp32 tournament prefilter (top-48) + fp64 exact re-rank --------
__global__ __launch_bounds__(256) void knn_kernel(const float* __restrict__ x,
                                                  int* __restrict__ idxout) {
    __shared__ float xs[NPTS], ys[NPTS], zs[NPTS];
    int t = threadIdx.x;
    int b = blockIdx.x / (NPTS / 4);
    int grp = blockIdx.x % (NPTS / 4);
    const float* xb = x + (size_t)b * 3 * NPTS;
    for (int i = t; i < NPTS; i += 256) {
        xs[i] = xb[i]; ys[i] = xb[NPTS + i]; zs[i] = xb[2 * NPTS + i];
    }
    __syncthreads();
    int wave = t >> 6, lane = t & 63;
    int n = grp * 4 + wave;
    float cx = xs[n], cy = ys[n], cz = zs[n];
    float sqn = -((cx * cx + cy * cy) + cz * cz);

    // fp32 keys: (ord(val) & ~31) | local slot j ; candidate = j*64 + lane
    unsigned key[32];
#pragma unroll
    for (int j = 0; j < 32; j++) {
        int cand = j * 64 + lane;
        float mx = xs[cand], my = ys[cand], mz = zs[cand];
        float dot = (cx * mx + cy * my) + cz * mz;
        float sqm = -((mx * mx + my * my) + mz * mz);
        float v = (sqn + 2.0f * dot) + sqm;
        unsigned u = __float_as_uint(v);
        unsigned ord = u ^ ((u >> 31) ? 0xFFFFFFFFu : 0x80000000u);
        key[j] = (ord & 0xFFFFFFE0u) | (unsigned)j;
    }
    // in-lane bitonic sort (descending), pure min/max network
#pragma unroll
    for (int k = 2; k <= 32; k <<= 1) {
#pragma unroll
        for (int j = k >> 1; j >= 1; j >>= 1) {
#pragma unroll
            for (int i = 0; i < 32; i++) {
                int l2 = i ^ j;
                if (l2 > i) {
                    unsigned a = key[i], bb = key[l2];
                    unsigned hi = a > bb ? a : bb, lo = a > bb ? bb : a;
                    if ((i & k) == 0) { key[i] = hi; key[l2] = lo; }
                    else              { key[i] = lo; key[l2] = hi; }
                }
            }
        }
    }
    // 48 tournament rounds: wave-max of heads, winner shifts its list
    int sg = 0;
    for (int r = 0; r < 48; r++) {
        unsigned m = key[0];
#pragma unroll
        for (int off = 32; off >= 1; off >>= 1) {
            unsigned om = __shfl_xor(m, off);
            m = om > m ? om : m;
        }
        unsigned long long ball = __ballot(key[0] == m);
        int bl = __ffsll(ball) - 1;
        int gidx = (int)(m & 31u) * 64 + bl;
        if (lane == r) sg = gidx;
        bool won = (lane == bl);
#pragma unroll
        for (int i = 0; i < 31; i++) key[i] = won ? key[i + 1] : key[i];
        key[31] = won ? 0u : key[31];
    }
    // fp64 exact re-rank of the 48 survivors (same expression order as before)
    double cxd = (double)cx, cyd = (double)cy, czd = (double)cz;
    double sqnd = -((cxd * cxd + cyd * cyd) + czd * czd);
    double v; int oid;
    if (lane < 48) {
        double mx = (double)xs[sg], my = (double)ys[sg], mz = (double)zs[sg];
        double dot = (cxd * mx + cyd * my) + czd * mz;
        double sqm = -((mx * mx + my * my) + mz * mz);
        v = (sqnd + 2.0 * dot) + sqm;
        oid = sg;
    } else {
        v = -1.0e300; oid = (1 << 28) + lane;
    }
    // 64-lane bitonic sort ascending by (val, idx-desc-tiebreak) => lane63 best
#pragma unroll
    for (int k = 2; k <= 64; k <<= 1) {
#pragma unroll
        for (int j = k >> 1; j >= 1; j >>= 1) {
            double ov = __shfl_xor(v, j);
            int oi = __shfl_xor(oid, j);
            bool amLow = (lane & j) == 0;
            bool asc = (lane & k) == 0;
            bool gt = (ov > v) || (ov == v && oi < oid);  // other sorts after me
            bool ga = gt != amLow;
            bool take = asc ? ga : !ga;
            if (take) { v = ov; oid = oi; }
        }
    }
    if (lane >= 32) idxout[((size_t)b * NPTS + n) * 32 + (63 - lane)] = oid;
}

// ---------------- feature transpose [B,64,N] -> bf16 [B,N,64] --------------
__global__ __launch_bounds__(256) void transpose_kernel(const float* __restrict__ feat,
                                                        unsigned short* __restrict__ fTb) {
    __shared__ float tile[64][65];
    int b = blockIdx.x / 32;
    int n0 = (blockIdx.x % 32) * 64;
    int t = threadIdx.x;
    int nt = t % 64, cg = t / 64;
    for (int cc = 0; cc < 16; cc++) {
        int c2 = cg * 16 + cc;
        tile[c2][nt] = feat[((size_t)b * 64 + c2) * NPTS + n0 + nt];
    }
    __syncthreads();
    int c2 = t % 64, ng = t / 64;
    for (int nn2 = 0; nn2 < 16; nn2++) {
        int n = ng * 16 + nn2;
        fTb[((size_t)b * NPTS + n0 + n) * 64 + c2] = f2bf(tile[c2][n]);
    }
}

// ---- weight prep: fold group-shuffle + MLP into WtT[oc][4096] bf16 --------
__global__ __launch_bounds__(256) void wprep2_kernel(
    const float* __restrict__ cw, const float* __restrict__ mlpw,
    const float* __restrict__ mb, const float* __restrict__ cb,
    unsigned short* __restrict__ WtT, float* __restrict__ cbw) {
    int oc = blockIdx.x;
    int t = threadIdx.x;
    for (int i = t; i < 2048; i += 256) {
        int f = i >> 5, col = i & 31;
        int r = (f % 24) * 4 + f / 24;
        WtT[(size_t)oc * KROW + i] = f2bf(cw[(size_t)oc * 3072 + r * 32 + col]);
    }
    for (int i = t; i < 2048; i += 256) {
        int j = i >> 5, col = i & 31;
        float s = 0.f;
        for (int o2 = 0; o2 < 32; o2++) {
            int f = 64 + o2;
            int r = (f % 24) * 4 + f / 24;
            s = fmaf(mlpw[o2 * 64 + j], cw[(size_t)oc * 3072 + r * 32 + col], s);
        }
        WtT[(size_t)oc * KROW + 2048 + i] = f2bf(s);
    }
    if (t == 0) {
        float s = cb[oc];
        for (int o2 = 0; o2 < 32; o2++) {
            int f = 64 + o2;
            int r = (f % 24) * 4 + f / 24;
            float rowsum = 0.f;
            for (int col = 0; col < 32; col++) rowsum += cw[(size_t)oc * 3072 + r * 32 + col];
            s = fmaf(mb[o2], rowsum, s);
        }
        cbw[oc] = s;
    }
}

__global__ void kprep_kernel(const float* __restrict__ ker, double* __restrict__ kerd) {
    int i = threadIdx.x;
    if (i < 96) kerd[i] = (double)ker[i];
}

// ---------------- per-point kernel: geometry, perm, G, O=G*perm (MFMA) -----
__global__ __launch_bounds__(256) void point2_kernel(
    const float* __restrict__ x, const unsigned short* __restrict__ fTb,
    const int* __restrict__ idx, const float* __restrict__ Bm,
    const double* __restrict__ kerd, unsigned short* __restrict__ Aof,
    int m_base, int m_count) {
    __shared__ double ldsbuf[4 * 1600];   // 4 waves * 12800 B
    int t = threadIdx.x;
    int wv = t >> 6, l = t & 63;
    int k = l & 31, h = l >> 5;
    char* base = (char*)ldsbuf + wv * 12800;
    double* pmd = (double*)base;                       // [32][33] f64 (8448 B)
    unsigned short* G = (unsigned short*)base;         // [128][40] bf16 (10240 B)
    unsigned short* PT = (unsigned short*)(base + 10240); // [32][40] bf16
    int lr = l & 15, lq = l >> 4;
    int gw = blockIdx.x * 4 + wv;
    int nw = gridDim.x * 4;

    for (int mi = gw; mi < m_count; mi += nw) {
        int m = m_base + mi;
        int b = m >> 11;
        int ik = idx[(size_t)m * 32 + k];
        const float* xb = x + (size_t)b * 3 * NPTS;
        float nx0 = xb[ik], ny0 = xb[NPTS + ik], nz0 = xb[2 * NPTS + ik];
        float cx = __shfl(nx0, 0), cy = __shfl(ny0, 0), cz = __shfl(nz0, 0);
        double rxd = (double)nx0 - (double)cx;
        double ryd = (double)ny0 - (double)cy;
        double rzd = (double)nz0 - (double)cz;
        float rx = (float)rxd, ry = (float)ryd, rz = (float)rzd;
        float dist = sqrtf((rx * rx + ry * ry) + rz * rz);

        // phase 2: p[k][c] fp64 (SGPR kernels), write own half
        double vd[32];
#pragma unroll
        for (int c = 0; c < 32; c++) {
            double v = rxd * kerd[c] + ryd * kerd[32 + c] + rzd * kerd[64 + c];
            if (k == 0 && c == 0) v += 1.0;
            vd[c] = v;
        }
#pragma unroll
        for (int cc = 0; cc < 16; cc++) {
            double vv = h ? vd[cc + 16] : vd[cc];
            pmd[k * 33 + h * 16 + cc] = vv;
        }
        asm volatile("" ::: "memory");

        // phase 3: fp64 top-3 threshold, fp32 softmax; column c = k
        int c = k;
        double pvd[32];
#pragma unroll
        for (int kk = 0; kk < 32; kk++) pvd[kk] = pmd[kk * 33 + c];
        double m1 = -1.0e300, m2 = -1.0e300, m3 = -1.0e300;
#pragma unroll
        for (int kk = 0; kk < 32; kk++) {
            double v = pvd[kk];
            if (v > m1) { m3 = m2; m2 = m1; m1 = v; }
            else if (v > m2) { m3 = m2; m2 = v; }
            else if (v > m3) { m3 = v; }
        }
        float pv[32];
        float ssum = 0.f;
#pragma unroll
        for (int kk = 0; kk < 32; kk++) {
            float e = (pvd[kk] >= m3) ? __expf((float)(pvd[kk] - m1)) : 0.f;
            pv[kk] = e; ssum += e;
        }
        float rs = 1.f / ssum;
#pragma unroll
        for (int kk = 0; kk < 32; kk++) pv[kk] *= rs;

        // permT row c (k-contiguous bf16); h=0 writes k 0..15, h=1 k 16..31
        unsigned w[16];
#pragma unroll
        for (int i = 0; i < 16; i++)
            w[i] = (unsigned)f2bf(pv[2 * i]) | ((unsigned)f2bf(pv[2 * i + 1]) << 16);
        unsigned s[8];
#pragma unroll
        for (int i = 0; i < 8; i++) s[i] = h ? w[8 + i] : w[i];
        *(uint4*)&PT[c * 40 + h * 16]     = make_uint4(s[0], s[1], s[2], s[3]);
        *(uint4*)&PT[c * 40 + h * 16 + 8] = make_uint4(s[4], s[5], s[6], s[7]);
        asm volatile("" ::: "memory");

        // G rows 0..63: gathered neighbor features (bf16), pair-pack across k
        {
            const unsigned short* fr = fTb + (((size_t)b * NPTS + ik) * 64 + h * 32);
            uint4 f0 = *(const uint4*)fr;
            uint4 f1 = *(const uint4*)(fr + 8);
            uint4 f2 = *(const uint4*)(fr + 16);
            uint4 f3 = *(const uint4*)(fr + 24);
            unsigned fw[16] = {f0.x, f0.y, f0.z, f0.w, f1.x, f1.y, f1.z, f1.w,
                               f2.x, f2.y, f2.z, f2.w, f3.x, f3.y, f3.z, f3.w};
#pragma unroll
            for (int c2 = 0; c2 < 16; c2++) {
                unsigned v = fw[c2];
                unsigned o = (unsigned)__shfl_xor((int)v, 1);
                unsigned wA = (k & 1) ? ((o & 0xFFFFu) | (v << 16)) : ((v & 0xFFFFu) | (o << 16));
                unsigned wB = (k & 1) ? ((o >> 16) | (v & 0xFFFF0000u)) : ((v >> 16) | (o & 0xFFFF0000u));
                int ch = h * 32 + 2 * c2 + (k & 1);
                unsigned wr = (k & 1) ? wB : wA;
                *(unsigned*)&G[ch * 40 + (k & ~1)] = wr;
            }
        }
        // G rows 64..127: Fourier features (SGPR B_mat, sin rows then cos rows)
        {
            float u[32];
#pragma unroll
            for (int f = 0; f < 32; f++) {
                float uu = cx * Bm[f];
                uu = fmaf(cy, Bm[32 + f], uu);
                uu = fmaf(cz, Bm[64 + f], uu);
                uu = fmaf(rx, Bm[96 + f], uu);
                uu = fmaf(ry, Bm[128 + f], uu);
                uu = fmaf(rz, Bm[160 + f], uu);
                uu = fmaf(dist, Bm[192 + f], uu);
                u[f] = 6.28318530717958647692f * uu;
            }
            float tv[32];
            if (h == 0) {
#pragma unroll
                for (int f = 0; f < 32; f++) tv[f] = __sinf(u[f]);
            } else {
#pragma unroll
                for (int f = 0; f < 32; f++) tv[f] = __cosf(u[f]);
            }
#pragma unroll
            for (int jj = 0; jj < 16; jj++) {
                unsigned b0 = f2bf(tv[jj]), b1 = f2bf(tv[jj + 16]);
                unsigned o0 = (unsigned)__shfl_xor((int)b0, 1);
                unsigned o1 = (unsigned)__shfl_xor((int)b1, 1);
                unsigned wr = (k & 1) ? ((o1 & 0xFFFFu) | (b1 << 16))
                                      : ((b0 & 0xFFFFu) | (o0 << 16));
                int ch = 64 + h * 32 + (k & 1) * 16 + jj;
                *(unsigned*)&G[ch * 40 + (k & ~1)] = wr;
            }
        }
        asm volatile("" ::: "memory");

        // O^T = perm^T * G^T via MFMA; store O[f][c] bf16 to Aof
        bf16x8 af0 = *(const bf16x8*)&PT[(lr)      * 40 + lq * 8];
        bf16x8 af1 = *(const bf16x8*)&PT[(16 + lr) * 40 + lq * 8];
        size_t obase = (size_t)mi * KROW;
#pragma unroll
        for (int fb = 0; fb < 8; fb++) {
            bf16x8 bfr = *(const bf16x8*)&G[(fb * 16 + lr) * 40 + lq * 8];
            f32x4 d0 = __builtin_amdgcn_mfma_f32_16x16x32_bf16(af0, bfr, (f32x4){0.f, 0.f, 0.f, 0.f}, 0, 0, 0);
            f32x4 d1 = __builtin_amdgcn_mfma_f32_16x16x32_bf16(af1, bfr, (f32x4){0.f, 0.f, 0.f, 0.f}, 0, 0, 0);
            int f = fb * 16 + lr;
            unsigned q0 = (unsigned)f2bf(d0.x) | ((unsigned)f2bf(d0.y) << 16);
            unsigned q1 = (unsigned)f2bf(d0.z) | ((unsigned)f2bf(d0.w) << 16);
            *(uint2*)&Aof[obase + f * 32 + lq * 4] = make_uint2(q0, q1);
            unsigned q2 = (unsigned)f2bf(d1.x) | ((unsigned)f2bf(d1.y) << 16);
            unsigned q3 = (unsigned)f2bf(d1.z) | ((unsigned)f2bf(d1.w) << 16);
            *(uint2*)&Aof[obase + f * 32 + 16 + lq * 4] = make_uint2(q2, q3);
        }
        asm volatile("" ::: "memory");
    }
}

// ---------------- conv GEMM (MFMA): out = Aof[CSx4096] * Wtot --------------
__global__ __launch_bounds__(256) void conv2_kernel(
    const unsigned short* __restrict__ A, const unsigned short* __restrict__ WtT,
    const float* __restrict__ cbw, float* __restrict__ outp, int m_base) {
    __shared__ unsigned short Al[64 * 72];
    __shared__ unsigned short Wl[64 * 72];
    int t = threadIdx.x;
    int wv = t >> 6, l = t & 63;
    int lr = l & 15, lq = l >> 4;
    int m0 = blockIdx.x * 64;
    int mr = t >> 3, kq = t & 7;
    f32x4 acc[4] = {};
    for (int ks = 0; ks < 64; ks++) {
        int k0 = ks * 64;
        uint4 a0 = *(const uint4*)&A[(size_t)(m0 + mr) * KROW + k0 + kq * 8];
        uint4 a1 = *(const uint4*)&A[(size_t)(m0 + mr + 32) * KROW + k0 + kq * 8];
        uint4 w0 = *(const uint4*)&WtT[(size_t)mr * KROW + k0 + kq * 8];
        uint4 w1 = *(const uint4*)&WtT[(size_t)(mr + 32) * KROW + k0 + kq * 8];
        __syncthreads();
        *(uint4*)&Al[mr * 72 + kq * 8] = a0;
        *(uint4*)&Al[(mr + 32) * 72 + kq * 8] = a1;
        *(uint4*)&Wl[mr * 72 + kq * 8] = w0;
        *(uint4*)&Wl[(mr + 32) * 72 + kq * 8] = w1;
        __syncthreads();
#pragma unroll
        for (int kk = 0; kk < 2; kk++) {
            bf16x8 af = *(const bf16x8*)&Al[(wv * 16 + lr) * 72 + kk * 32 + lq * 8];
#pragma unroll
            for (int ocb = 0; ocb < 4; ocb++) {
                bf16x8 wf = *(const bf16x8*)&Wl[(ocb * 16 + lr) * 72 + kk * 32 + lq * 8];
                acc[ocb] = __builtin_amdgcn_mfma_f32_16x16x32_bf16(af, wf, acc[ocb], 0, 0, 0);
            }
        }
    }
    int m = m_base + m0 + wv * 16 + lq * 4;
    int b = m >> 11, n = m & 2047;
#pragma unroll
    for (int ocb = 0; ocb < 4; ocb++) {
        int oc = ocb * 16 + lr;
        float bias = cbw[oc];
        float4 v = make_float4(acc[ocb].x + bias, acc[ocb].y + bias,
                               acc[ocb].z + bias, acc[ocb].w + bias);
        *(float4*)&outp[((size_t)(b * 64 + oc)) * 2048 + n] = v;
    }
}

// ---------------- BatchNorm -----------------------------------------------
__global__ __launch_bounds__(256) void bn1_kernel(const float* __restrict__ outp,
                                                  float* __restrict__ sums) {
    int c = blockIdx.x, t = threadIdx.x;
    float s = 0.0f, s2 = 0.0f;
    for (int b = 0; b < NBATCH; b++) {
        const float* p = outp + ((size_t)b * 64 + c) * NPTS;
        for (int i = t; i < NPTS; i += 256) {
            float v = p[i];
            s += v; s2 = fmaf(v, v, s2);
        }
    }
    __shared__ float r1[256], r2[256];
    r1[t] = s; r2[t] = s2;
    __syncthreads();
    for (int st = 128; st > 0; st >>= 1) {
        if (t < st) { r1[t] += r1[t + st]; r2[t] += r2[t + st]; }
        __syncthreads();
    }
    if (t == 0) { sums[c] = r1[0]; sums[64 + c] = r2[0]; }
}

__global__ __launch_bounds__(256) void bn2_kernel(float* __restrict__ outp,
                                                  const float* __restrict__ sums,
                                                  const float* __restrict__ gamma,
                                                  const float* __restrict__ beta) {
    int i = blockIdx.x * 256 + threadIdx.x;
    if (i >= MTOT * 64) return;
    int c = (i >> 11) & 63;
    float mean = sums[c] * (1.0f / (float)MTOT);
    float var = sums[64 + c] * (1.0f / (float)MTOT) - mean * mean;
    float inv = rsqrtf(var + 1e-5f);
    outp[i] = fmaf(gamma[c], (outp[i] - mean) * inv, beta[c]);
}

extern "C" void kernel_launch(void* const* d_in, const int* in_sizes, int n_in,
                              void* d_out, int out_size, void* d_ws, size_t ws_size,
                              hipStream_t stream) {
    (void)in_sizes; (void)n_in; (void)out_size;
    const float* x    = (const float*)d_in[0];
    const float* fea  = (const float*)d_in[1];
    const float* Bm   = (const float*)d_in[2];
    const float* ker  = (const float*)d_in[3];
    const float* mw   = (const float*)d_in[4];
    const float* mb   = (const float*)d_in[5];
    const float* cw   = (const float*)d_in[6];
    const float* cb   = (const float*)d_in[7];
    const float* gam  = (const float*)d_in[8];
    const float* bet  = (const float*)d_in[9];
    float* outp = (float*)d_out;

    char* wsb = (char*)d_ws;
    size_t off = 0;
    auto carve = [&](size_t sz) {
        void* p = wsb + off;
        off = (off + sz + 255) & ~(size_t)255;
        return p;
    };
    unsigned short* fTb  = (unsigned short*)carve((size_t)MTOT * 64 * 2);
    int*            idxw = (int*)carve((size_t)MTOT * 32 * 4);
    unsigned short* WtT  = (unsigned short*)carve((size_t)OUTC * KROW * 2);
    float*          cbw  = (float*)carve(64 * 4);
    double*         kerd = (double*)carve(96 * 8);
    float*          sums = (float*)carve(2 * 64 * 4);
    size_t fixedEnd = off;
    int CS = 16384;
    while (fixedEnd + (size_t)CS * KROW * 2 > ws_size && CS > 2048) CS >>= 1;
    unsigned short* Aof = (unsigned short*)(wsb + fixedEnd);

    knn_kernel<<<NBATCH * (NPTS / 4), 256, 0, stream>>>(x, idxw);
    transpose_kernel<<<NBATCH * 32, 256, 0, stream>>>(fea, fTb);
    wprep2_kernel<<<64, 256, 0, stream>>>(cw, mw, mb, cb, WtT, cbw);
    kprep_kernel<<<1, 128, 0, stream>>>(ker, kerd);

    for (int c0 = 0; c0 < MTOT; c0 += CS) {
        point2_kernel<<<768, 256, 0, stream>>>(x, fTb, idxw, Bm, kerd, Aof, c0, CS);
        conv2_kernel<<<CS / 64, 256, 0, stream>>>(Aof, WtT, cbw, outp, c0);
    }
    bn1_kernel<<<64, 256, 0, stream>>>(outp, sums);
    bn2_kernel<<<(MTOT * 64 + 255) / 256, 256, 0, stream>>>(outp, sums, gam, bet);
}

// Round 5
// 258.534 us; speedup vs baseline: 3.1867x; 1.2670x over previous
//
#include <hip/hip_runtime.h>
#include <math.h>

#define NPTS 2048
#define NBATCH 8
#define MTOT (NBATCH*NPTS)
#define KROW 4096   // conv K: 128 rows * 32 cols
#define OUTC 64

using bf16x8 = __attribute__((ext_vector_type(8))) short;
using f32x4  = __attribute__((ext_vector_type(4))) float;

__device__ __forceinline__ unsigned short f2bf(float f) {
    unsigned u = __float_as_uint(f);
    unsigned r = u + 0x7FFFu + ((u >> 16) & 1u);
    return (unsigned short)(r >> 16);
}

__device__ __forceinline__ unsigned wave_max_u32(unsigned v) {
    // canonical GCN wave64 reduce: result lands in lane 63
    int x = (int)v, t;
    t = __builtin_amdgcn_update_dpp(x, x, 0x111, 0xF, 0xF, false); x = ((unsigned)t > (unsigned)x) ? t : x;
    t = __builtin_amdgcn_update_dpp(x, x, 0x112, 0xF, 0xF, false); x = ((unsigned)t > (unsigned)x) ? t : x;
    t = __builtin_amdgcn_update_dpp(x, x, 0x114, 0xF, 0xF, false); x = ((unsigned)t > (unsigned)x) ? t : x;
    t = __builtin_amdgcn_update_dpp(x, x, 0x118, 0xF, 0xF, false); x = ((unsigned)t > (unsigned)x) ? t : x;
    t = __builtin_amdgcn_update_dpp(x, x, 0x142, 0xa, 0xF, false); x = ((unsigned)t > (unsigned)x) ? t : x;
    t = __builtin_amdgcn_update_dpp(x, x, 0x143, 0xc, 0xF, false); x = ((unsigned)t > (unsigned)x) ? t : x;
    return (unsigned)__builtin_amdgcn_readlane(x, 63);
}

// ---- KNN: fp32 tournament prefilter (top-40) + fp64 exact re-rank --------
__global__ __launch_bounds__(256) void knn_kernel(const float* __restrict__ x,
                                                  int* __restrict__ idxout) {
    __shared__ float xs[NPTS], ys[NPTS], zs[NPTS], sqs[NPTS];
    int t = threadIdx.x;
    int b = blockIdx.x / (NPTS / 4);
    int grp = blockIdx.x % (NPTS / 4);
    const float* xb = x + (size_t)b * 3 * NPTS;
    for (int i = t; i < NPTS; i += 256) {
        float vx = xb[i], vy = xb[NPTS + i], vz = xb[2 * NPTS + i];
        xs[i] = vx; ys[i] = vy; zs[i] = vz;
        sqs[i] = -((vx * vx + vy * vy) + vz * vz);
    }
    __syncthreads();
    int wave = t >> 6, lane = t & 63;
    int n = grp * 4 + wave;
    float cx = xs[n], cy = ys[n], cz = zs[n];
    float sqn = sqs[n];
    float cx2 = 2.0f * cx, cy2 = 2.0f * cy, cz2 = 2.0f * cz;

    // fp32 keys: (ord(val) & ~31) | local slot j ; candidate = j*64 + lane
    unsigned key[32];
#pragma unroll
    for (int j = 0; j < 32; j++) {
        int cand = j * 64 + lane;
        float v = sqn + sqs[cand];
        v = fmaf(cx2, xs[cand], v);
        v = fmaf(cy2, ys[cand], v);
        v = fmaf(cz2, zs[cand], v);
        unsigned u = __float_as_uint(v);
        unsigned ord = u ^ ((u >> 31) ? 0xFFFFFFFFu : 0x80000000u);
        key[j] = (ord & 0xFFFFFFE0u) | (unsigned)j;
    }
    // in-lane bitonic sort (descending); only top-12 consumed (DCE prunes rest)
#pragma unroll
    for (int k = 2; k <= 32; k <<= 1) {
#pragma unroll
        for (int j = k >> 1; j >= 1; j >>= 1) {
#pragma unroll
            for (int i = 0; i < 32; i++) {
                int l2 = i ^ j;
                if (l2 > i) {
                    unsigned a = key[i], bb = key[l2];
                    unsigned hi = a > bb ? a : bb, lo = a > bb ? bb : a;
                    if ((i & k) == 0) { key[i] = hi; key[l2] = lo; }
                    else              { key[i] = lo; key[l2] = hi; }
                }
            }
        }
    }
    // 40 tournament rounds: DPP wave-max of heads; winner shifts (cap 12)
    int sg = 0;
    for (int r = 0; r < 40; r++) {
        unsigned m = wave_max_u32(key[0]);
        unsigned long long ball = __ballot(key[0] == m);
        int bl = __ffsll(ball) - 1;
        int gidx = (int)(m & 31u) * 64 + bl;
        if (lane == r) sg = gidx;
        bool won = (lane == bl);
#pragma unroll
        for (int i = 0; i < 11; i++) key[i] = won ? key[i + 1] : key[i];
        key[11] = won ? 0u : key[11];
    }
    // fp64 exact re-rank of the 40 survivors (same expression order as before)
    double cxd = (double)cx, cyd = (double)cy, czd = (double)cz;
    double sqnd = -((cxd * cxd + cyd * cyd) + czd * czd);
    double v; int oid;
    if (lane < 40) {
        double mx = (double)xs[sg], my = (double)ys[sg], mz = (double)zs[sg];
        double dot = (cxd * mx + cyd * my) + czd * mz;
        double sqm = -((mx * mx + my * my) + mz * mz);
        v = (sqnd + 2.0 * dot) + sqm;
        oid = sg;
    } else {
        v = -1.0e300; oid = (1 << 28) + lane;
    }
    // 64-lane bitonic sort ascending by (val, idx-desc-tiebreak) => lane63 best
#pragma unroll
    for (int k = 2; k <= 64; k <<= 1) {
#pragma unroll
        for (int j = k >> 1; j >= 1; j >>= 1) {
            double ov = __shfl_xor(v, j);
            int oi = __shfl_xor(oid, j);
            bool amLow = (lane & j) == 0;
            bool asc = (lane & k) == 0;
            bool gt = (ov > v) || (ov == v && oi < oid);  // other sorts after me
            bool ga = gt != amLow;
            bool take = asc ? ga : !ga;
            if (take) { v = ov; oid = oi; }
        }
    }
    if (lane >= 32) idxout[((size_t)b * NPTS + n) * 32 + (63 - lane)] = oid;
}

// ---------------- feature transpose [B,64,N] -> bf16 [B,N,64] --------------
__global__ __launch_bounds__(256) void transpose_kernel(const float* __restrict__ feat,
                                                        unsigned short* __restrict__ fTb) {
    __shared__ float tile[64][65];
    int b = blockIdx.x / 32;
    int n0 = (blockIdx.x % 32) * 64;
    int t = threadIdx.x;
    int nt = t % 64, cg = t / 64;
    for (int cc = 0; cc < 16; cc++) {
        int c2 = cg * 16 + cc;
        tile[c2][nt] = feat[((size_t)b * 64 + c2) * NPTS + n0 + nt];
    }
    __syncthreads();
    int c2 = t % 64, ng = t / 64;
    for (int nn2 = 0; nn2 < 16; nn2++) {
        int n = ng * 16 + nn2;
        fTb[((size_t)b * NPTS + n0 + n) * 64 + c2] = f2bf(tile[c2][n]);
    }
}

// ---- weight prep: fold group-shuffle + MLP into WtT[oc][4096] bf16 --------
__global__ __launch_bounds__(256) void wprep2_kernel(
    const float* __restrict__ cw, const float* __restrict__ mlpw,
    const float* __restrict__ mb, const float* __restrict__ cb,
    unsigned short* __restrict__ WtT, float* __restrict__ cbw) {
    int oc = blockIdx.x;
    int t = threadIdx.x;
    for (int i = t; i < 2048; i += 256) {
        int f = i >> 5, col = i & 31;
        int r = (f % 24) * 4 + f / 24;
        WtT[(size_t)oc * KROW + i] = f2bf(cw[(size_t)oc * 3072 + r * 32 + col]);
    }
    for (int i = t; i < 2048; i += 256) {
        int j = i >> 5, col = i & 31;
        float s = 0.f;
        for (int o2 = 0; o2 < 32; o2++) {
            int f = 64 + o2;
            int r = (f % 24) * 4 + f / 24;
            s = fmaf(mlpw[o2 * 64 + j], cw[(size_t)oc * 3072 + r * 32 + col], s);
        }
        WtT[(size_t)oc * KROW + 2048 + i] = f2bf(s);
    }
    if (t == 0) {
        float s = cb[oc];
        for (int o2 = 0; o2 < 32; o2++) {
            int f = 64 + o2;
            int r = (f % 24) * 4 + f / 24;
            float rowsum = 0.f;
            for (int col = 0; col < 32; col++) rowsum += cw[(size_t)oc * 3072 + r * 32 + col];
            s = fmaf(mb[o2], rowsum, s);
        }
        cbw[oc] = s;
    }
}

__global__ void kprep_kernel(const float* __restrict__ ker, double* __restrict__ kerd) {
    int i = threadIdx.x;
    if (i < 96) kerd[i] = (double)ker[i];
}

// ---------------- per-point kernel: geometry, perm, G, O=G*perm (MFMA) -----
__global__ __launch_bounds__(256) void point2_kernel(
    const float* __restrict__ x, const unsigned short* __restrict__ fTb,
    const int* __restrict__ idx, const float* __restrict__ Bm,
    const double* __restrict__ kerd, unsigned short* __restrict__ Aof,
    int m_base, int m_count) {
    __shared__ double ldsbuf[4 * 1600];   // 4 waves * 12800 B
    int t = threadIdx.x;
    int wv = t >> 6, l = t & 63;
    int k = l & 31, h = l >> 5;
    char* base = (char*)ldsbuf + wv * 12800;
    double* pmd = (double*)base;                       // [32][33] f64 (8448 B)
    unsigned short* G = (unsigned short*)base;         // [128][40] bf16 (10240 B)
    unsigned short* PT = (unsigned short*)(base + 10240); // [32][40] bf16
    int lr = l & 15, lq = l >> 4;
    int gw = blockIdx.x * 4 + wv;
    int nw = gridDim.x * 4;

    for (int mi = gw; mi < m_count; mi += nw) {
        int m = m_base + mi;
        int b = m >> 11;
        int ik = idx[(size_t)m * 32 + k];
        const float* xb = x + (size_t)b * 3 * NPTS;
        float nx0 = xb[ik], ny0 = xb[NPTS + ik], nz0 = xb[2 * NPTS + ik];
        float cx = __shfl(nx0, 0), cy = __shfl(ny0, 0), cz = __shfl(nz0, 0);
        double rxd = (double)nx0 - (double)cx;
        double ryd = (double)ny0 - (double)cy;
        double rzd = (double)nz0 - (double)cz;
        float rx = (float)rxd, ry = (float)ryd, rz = (float)rzd;
        float dist = sqrtf((rx * rx + ry * ry) + rz * rz);

        // phase 2: p[k][c] fp64 (SGPR kernels), write own half
        double vd[32];
#pragma unroll
        for (int c = 0; c < 32; c++) {
            double v = rxd * kerd[c] + ryd * kerd[32 + c] + rzd * kerd[64 + c];
            if (k == 0 && c == 0) v += 1.0;
            vd[c] = v;
        }
#pragma unroll
        for (int cc = 0; cc < 16; cc++) {
            double vv = h ? vd[cc + 16] : vd[cc];
            pmd[k * 33 + h * 16 + cc] = vv;
        }
        asm volatile("" ::: "memory");

        // phase 3: fp64 top-3 threshold, fp32 softmax; column c = k
        int c = k;
        double pvd[32];
#pragma unroll
        for (int kk = 0; kk < 32; kk++) pvd[kk] = pmd[kk * 33 + c];
        double m1 = -1.0e300, m2 = -1.0e300, m3 = -1.0e300;
#pragma unroll
        for (int kk = 0; kk < 32; kk++) {
            double v = pvd[kk];
            if (v > m1) { m3 = m2; m2 = m1; m1 = v; }
            else if (v > m2) { m3 = m2; m2 = v; }
            else if (v > m3) { m3 = v; }
        }
        float pv[32];
        float ssum = 0.f;
#pragma unroll
        for (int kk = 0; kk < 32; kk++) {
            float e = (pvd[kk] >= m3) ? __expf((float)(pvd[kk] - m1)) : 0.f;
            pv[kk] = e; ssum += e;
        }
        float rs = 1.f / ssum;
#pragma unroll
        for (int kk = 0; kk < 32; kk++) pv[kk] *= rs;

        // permT row c (k-contiguous bf16); h=0 writes k 0..15, h=1 k 16..31
        unsigned w[16];
#pragma unroll
        for (int i = 0; i < 16; i++)
            w[i] = (unsigned)f2bf(pv[2 * i]) | ((unsigned)f2bf(pv[2 * i + 1]) << 16);
        unsigned s[8];
#pragma unroll
        for (int i = 0; i < 8; i++) s[i] = h ? w[8 + i] : w[i];
        *(uint4*)&PT[c * 40 + h * 16]     = make_uint4(s[0], s[1], s[2], s[3]);
        *(uint4*)&PT[c * 40 + h * 16 + 8] = make_uint4(s[4], s[5], s[6], s[7]);
        asm volatile("" ::: "memory");

        // G rows 0..63: gathered neighbor features (bf16), pair-pack across k
        {
            const unsigned short* fr = fTb + (((size_t)b * NPTS + ik) * 64 + h * 32);
            uint4 f0 = *(const uint4*)fr;
            uint4 f1 = *(const uint4*)(fr + 8);
            uint4 f2 = *(const uint4*)(fr + 16);
            uint4 f3 = *(const uint4*)(fr + 24);
            unsigned fw[16] = {f0.x, f0.y, f0.z, f0.w, f1.x, f1.y, f1.z, f1.w,
                               f2.x, f2.y, f2.z, f2.w, f3.x, f3.y, f3.z, f3.w};
#pragma unroll
            for (int c2 = 0; c2 < 16; c2++) {
                unsigned v = fw[c2];
                unsigned o = (unsigned)__shfl_xor((int)v, 1);
                unsigned wA = (k & 1) ? ((o & 0xFFFFu) | (v << 16)) : ((v & 0xFFFFu) | (o << 16));
                unsigned wB = (k & 1) ? ((o >> 16) | (v & 0xFFFF0000u)) : ((v >> 16) | (o & 0xFFFF0000u));
                int ch = h * 32 + 2 * c2 + (k & 1);
                unsigned wr = (k & 1) ? wB : wA;
                *(unsigned*)&G[ch * 40 + (k & ~1)] = wr;
            }
        }
        // G rows 64..127: Fourier features (SGPR B_mat, sin rows then cos rows)
        {
            float u[32];
#pragma unroll
            for (int f = 0; f < 32; f++) {
                float uu = cx * Bm[f];
                uu = fmaf(cy, Bm[32 + f], uu);
                uu = fmaf(cz, Bm[64 + f], uu);
                uu = fmaf(rx, Bm[96 + f], uu);
                uu = fmaf(ry, Bm[128 + f], uu);
                uu = fmaf(rz, Bm[160 + f], uu);
                uu = fmaf(dist, Bm[192 + f], uu);
                u[f] = 6.28318530717958647692f * uu;
            }
            float tv[32];
            if (h == 0) {
#pragma unroll
                for (int f = 0; f < 32; f++) tv[f] = __sinf(u[f]);
            } else {
#pragma unroll
                for (int f = 0; f < 32; f++) tv[f] = __cosf(u[f]);
            }
#pragma unroll
            for (int jj = 0; jj < 16; jj++) {
                unsigned b0 = f2bf(tv[jj]), b1 = f2bf(tv[jj + 16]);
                unsigned o0 = (unsigned)__shfl_xor((int)b0, 1);
                unsigned o1 = (unsigned)__shfl_xor((int)b1, 1);
                unsigned wr = (k & 1) ? ((o1 & 0xFFFFu) | (b1 << 16))
                                      : ((b0 & 0xFFFFu) | (o0 << 16));
                int ch = 64 + h * 32 + (k & 1) * 16 + jj;
                *(unsigned*)&G[ch * 40 + (k & ~1)] = wr;
            }
        }
        asm volatile("" ::: "memory");

        // O^T = perm^T * G^T via MFMA; store O[f][c] bf16 to Aof
        bf16x8 af0 = *(const bf16x8*)&PT[(lr)      * 40 + lq * 8];
        bf16x8 af1 = *(const bf16x8*)&PT[(16 + lr) * 40 + lq * 8];
        size_t obase = (size_t)mi * KROW;
#pragma unroll
        for (int fb = 0; fb < 8; fb++) {
            bf16x8 bfr = *(const bf16x8*)&G[(fb * 16 + lr) * 40 + lq * 8];
            f32x4 d0 = __builtin_amdgcn_mfma_f32_16x16x32_bf16(af0, bfr, (f32x4){0.f, 0.f, 0.f, 0.f}, 0, 0, 0);
            f32x4 d1 = __builtin_amdgcn_mfma_f32_16x16x32_bf16(af1, bfr, (f32x4){0.f, 0.f, 0.f, 0.f}, 0, 0, 0);
            int f = fb * 16 + lr;
            unsigned q0 = (unsigned)f2bf(d0.x) | ((unsigned)f2bf(d0.y) << 16);
            unsigned q1 = (unsigned)f2bf(d0.z) | ((unsigned)f2bf(d0.w) << 16);
            *(uint2*)&Aof[obase + f * 32 + lq * 4] = make_uint2(q0, q1);
            unsigned q2 = (unsigned)f2bf(d1.x) | ((unsigned)f2bf(d1.y) << 16);
            unsigned q3 = (unsigned)f2bf(d1.z) | ((unsigned)f2bf(d1.w) << 16);
            *(uint2*)&Aof[obase + f * 32 + 16 + lq * 4] = make_uint2(q2, q3);
        }
        asm volatile("" ::: "memory");
    }
}

// ---------------- conv GEMM (MFMA): out = Aof[CSx4096] * Wtot --------------
__global__ __launch_bounds__(256) void conv2_kernel(
    const unsigned short* __restrict__ A, const unsigned short* __restrict__ WtT,
    const float* __restrict__ cbw, float* __restrict__ outp, int m_base) {
    __shared__ unsigned short Al[64 * 72];
    __shared__ unsigned short Wl[64 * 72];
    int t = threadIdx.x;
    int wv = t >> 6, l = t & 63;
    int lr = l & 15, lq = l >> 4;
    int m0 = blockIdx.x * 64;
    int mr = t >> 3, kq = t & 7;
    f32x4 acc[4] = {};
    for (int ks = 0; ks < 64; ks++) {
        int k0 = ks * 64;
        uint4 a0 = *(const uint4*)&A[(size_t)(m0 + mr) * KROW + k0 + kq * 8];
        uint4 a1 = *(const uint4*)&A[(size_t)(m0 + mr + 32) * KROW + k0 + kq * 8];
        uint4 w0 = *(const uint4*)&WtT[(size_t)mr * KROW + k0 + kq * 8];
        uint4 w1 = *(const uint4*)&WtT[(size_t)(mr + 32) * KROW + k0 + kq * 8];
        __syncthreads();
        *(uint4*)&Al[mr * 72 + kq * 8] = a0;
        *(uint4*)&Al[(mr + 32) * 72 + kq * 8] = a1;
        *(uint4*)&Wl[mr * 72 + kq * 8] = w0;
        *(uint4*)&Wl[(mr + 32) * 72 + kq * 8] = w1;
        __syncthreads();
#pragma unroll
        for (int kk = 0; kk < 2; kk++) {
            bf16x8 af = *(const bf16x8*)&Al[(wv * 16 + lr) * 72 + kk * 32 + lq * 8];
#pragma unroll
            for (int ocb = 0; ocb < 4; ocb++) {
                bf16x8 wf = *(const bf16x8*)&Wl[(ocb * 16 + lr) * 72 + kk * 32 + lq * 8];
                acc[ocb] = __builtin_amdgcn_mfma_f32_16x16x32_bf16(af, wf, acc[ocb], 0, 0, 0);
            }
        }
    }
    int m = m_base + m0 + wv * 16 + lq * 4;
    int b = m >> 11, n = m & 2047;
#pragma unroll
    for (int ocb = 0; ocb < 4; ocb++) {
        int oc = ocb * 16 + lr;
        float bias = cbw[oc];
        float4 v = make_float4(acc[ocb].x + bias, acc[ocb].y + bias,
                               acc[ocb].z + bias, acc[ocb].w + bias);
        *(float4*)&outp[((size_t)(b * 64 + oc)) * 2048 + n] = v;
    }
}

// ---------------- BatchNorm -----------------------------------------------
__global__ __launch_bounds__(256) void bn1_kernel(const float* __restrict__ outp,
                                                  float* __restrict__ sums) {
    int c = blockIdx.x, t = threadIdx.x;
    float s = 0.0f, s2 = 0.0f;
    for (int b = 0; b < NBATCH; b++) {
        const float* p = outp + ((size_t)b * 64 + c) * NPTS;
        for (int i = t; i < NPTS; i += 256) {
            float v = p[i];
            s += v; s2 = fmaf(v, v, s2);
        }
    }
    __shared__ float r1[256], r2[256];
    r1[t] = s; r2[t] = s2;
    __syncthreads();
    for (int st = 128; st > 0; st >>= 1) {
        if (t < st) { r1[t] += r1[t + st]; r2[t] += r2[t + st]; }
        __syncthreads();
    }
    if (t == 0) { sums[c] = r1[0]; sums[64 + c] = r2[0]; }
}

__global__ __launch_bounds__(256) void bn2_kernel(float* __restrict__ outp,
                                                  const float* __restrict__ sums,
                                                  const float* __restrict__ gamma,
                                                  const float* __restrict__ beta) {
    int i = blockIdx.x * 256 + threadIdx.x;
    if (i >= MTOT * 64) return;
    int c = (i >> 11) & 63;
    float mean = sums[c] * (1.0f / (float)MTOT);
    float var = sums[64 + c] * (1.0f / (float)MTOT) - mean * mean;
    float inv = rsqrtf(var + 1e-5f);
    outp[i] = fmaf(gamma[c], (outp[i] - mean) * inv, beta[c]);
}

extern "C" void kernel_launch(void* const* d_in, const int* in_sizes, int n_in,
                              void* d_out, int out_size, void* d_ws, size_t ws_size,
                              hipStream_t stream) {
    (void)in_sizes; (void)n_in; (void)out_size;
    const float* x    = (const float*)d_in[0];
    const float* fea  = (const float*)d_in[1];
    const float* Bm   = (const float*)d_in[2];
    const float* ker  = (const float*)d_in[3];
    const float* mw   = (const float*)d_in[4];
    const float* mb   = (const float*)d_in[5];
    const float* cw   = (const float*)d_in[6];
    const float* cb   = (const float*)d_in[7];
    const float* gam  = (const float*)d_in[8];
    const float* bet  = (const float*)d_in[9];
    float* outp = (float*)d_out;

    char* wsb = (char*)d_ws;
    size_t off = 0;
    auto carve = [&](size_t sz) {
        void* p = wsb + off;
        off = (off + sz + 255) & ~(size_t)255;
        return p;
    };
    unsigned short* fTb  = (unsigned short*)carve((size_t)MTOT * 64 * 2);
    int*            idxw = (int*)carve((size_t)MTOT * 32 * 4);
    unsigned short* WtT  = (unsigned short*)carve((size_t)OUTC * KROW * 2);
    float*          cbw  = (float*)carve(64 * 4);
    double*         kerd = (double*)carve(96 * 8);
    float*          sums = (float*)carve(2 * 64 * 4);
    size_t fixedEnd = off;
    int CS = 16384;
    while (fixedEnd + (size_t)CS * KROW * 2 > ws_size && CS > 2048) CS >>= 1;
    unsigned short* Aof = (unsigned short*)(wsb + fixedEnd);

    knn_kernel<<<NBATCH * (NPTS / 4), 256, 0, stream>>>(x, idxw);
    transpose_kernel<<<NBATCH * 32, 256, 0, stream>>>(fea, fTb);
    wprep2_kernel<<<64, 256, 0, stream>>>(cw, mw, mb, cb, WtT, cbw);
    kprep_kernel<<<1, 128, 0, stream>>>(ker, kerd);

    for (int c0 = 0; c0 < MTOT; c0 += CS) {
        point2_kernel<<<768, 256, 0, stream>>>(x, fTb, idxw, Bm, kerd, Aof, c0, CS);
        conv2_kernel<<<CS / 64, 256, 0, stream>>>(Aof, WtT, cbw, outp, c0);
    }
    bn1_kernel<<<64, 256, 0, stream>>>(outp, sums);
    bn2_kernel<<<(MTOT * 64 + 255) / 256, 256, 0, stream>>>(outp, sums, gam, bet);
}

// Round 7
// 218.195 us; speedup vs baseline: 3.7758x; 1.1849x over previous
//
#include <hip/hip_runtime.h>
#include <math.h>

#define NPTS 2048
#define NBATCH 8
#define MTOT (NBATCH*NPTS)
#define KROW 4096   // conv K: 128 rows * 32 cols
#define OUTC 64

using bf16x8 = __attribute__((ext_vector_type(8))) short;
using f32x4  = __attribute__((ext_vector_type(4))) float;

__device__ __forceinline__ unsigned short f2bf(float f) {
    unsigned u = __float_as_uint(f);
    unsigned r = u + 0x7FFFu + ((u >> 16) & 1u);
    return (unsigned short)(r >> 16);
}

__device__ __forceinline__ double bcast_d(double v, int srclane) {
    int lo = __builtin_amdgcn_readlane(__double2loint(v), srclane);
    int hi = __builtin_amdgcn_readlane(__double2hiint(v), srclane);
    return __hiloint2double(hi, lo);
}

__device__ __forceinline__ unsigned wave_max_u32(unsigned v) {
    int x = (int)v, t;
    t = __builtin_amdgcn_update_dpp(x, x, 0x111, 0xF, 0xF, false); x = ((unsigned)t > (unsigned)x) ? t : x;
    t = __builtin_amdgcn_update_dpp(x, x, 0x112, 0xF, 0xF, false); x = ((unsigned)t > (unsigned)x) ? t : x;
    t = __builtin_amdgcn_update_dpp(x, x, 0x114, 0xF, 0xF, false); x = ((unsigned)t > (unsigned)x) ? t : x;
    t = __builtin_amdgcn_update_dpp(x, x, 0x118, 0xF, 0xF, false); x = ((unsigned)t > (unsigned)x) ? t : x;
    t = __builtin_amdgcn_update_dpp(x, x, 0x142, 0xa, 0xF, false); x = ((unsigned)t > (unsigned)x) ? t : x;
    t = __builtin_amdgcn_update_dpp(x, x, 0x143, 0xc, 0xF, false); x = ((unsigned)t > (unsigned)x) ? t : x;
    return (unsigned)__builtin_amdgcn_readlane(x, 63);
}

// ---- KNN: fp32 tournament prefilter (top-40) + fp64 exact re-rank --------
__global__ __launch_bounds__(256) void knn_kernel(const float* __restrict__ x,
                                                  int* __restrict__ idxout) {
    __shared__ float xs[NPTS], ys[NPTS], zs[NPTS], sqs[NPTS];
    int t = threadIdx.x;
    int b = blockIdx.x / (NPTS / 4);
    int grp = blockIdx.x % (NPTS / 4);
    const float* xb = x + (size_t)b * 3 * NPTS;
    for (int i = t; i < NPTS; i += 256) {
        float vx = xb[i], vy = xb[NPTS + i], vz = xb[2 * NPTS + i];
        xs[i] = vx; ys[i] = vy; zs[i] = vz;
        sqs[i] = -((vx * vx + vy * vy) + vz * vz);
    }
    __syncthreads();
    int wave = t >> 6, lane = t & 63;
    int n = grp * 4 + wave;
    float cx = xs[n], cy = ys[n], cz = zs[n];
    float sqn = sqs[n];
    float cx2 = 2.0f * cx, cy2 = 2.0f * cy, cz2 = 2.0f * cz;

    unsigned key[32];
#pragma unroll
    for (int j = 0; j < 32; j++) {
        int cand = j * 64 + lane;
        float v = sqn + sqs[cand];
        v = fmaf(cx2, xs[cand], v);
        v = fmaf(cy2, ys[cand], v);
        v = fmaf(cz2, zs[cand], v);
        unsigned u = __float_as_uint(v);
        unsigned ord = u ^ ((u >> 31) ? 0xFFFFFFFFu : 0x80000000u);
        key[j] = (ord & 0xFFFFFFE0u) | (unsigned)j;
    }
#pragma unroll
    for (int k = 2; k <= 32; k <<= 1) {
#pragma unroll
        for (int j = k >> 1; j >= 1; j >>= 1) {
#pragma unroll
            for (int i = 0; i < 32; i++) {
                int l2 = i ^ j;
                if (l2 > i) {
                    unsigned a = key[i], bb = key[l2];
                    unsigned hi = a > bb ? a : bb, lo = a > bb ? bb : a;
                    if ((i & k) == 0) { key[i] = hi; key[l2] = lo; }
                    else              { key[i] = lo; key[l2] = hi; }
                }
            }
        }
    }
    int sg = 0;
    for (int r = 0; r < 40; r++) {
        unsigned m = wave_max_u32(key[0]);
        unsigned long long ball = __ballot(key[0] == m);
        int bl = __ffsll(ball) - 1;
        int gidx = (int)(m & 31u) * 64 + bl;
        if (lane == r) sg = gidx;
        bool won = (lane == bl);
#pragma unroll
        for (int i = 0; i < 11; i++) key[i] = won ? key[i + 1] : key[i];
        key[11] = won ? 0u : key[11];
    }
    double cxd = (double)cx, cyd = (double)cy, czd = (double)cz;
    double sqnd = -((cxd * cxd + cyd * cyd) + czd * czd);
    double v; int oid;
    if (lane < 40) {
        double mx = (double)xs[sg], my = (double)ys[sg], mz = (double)zs[sg];
        double dot = (cxd * mx + cyd * my) + czd * mz;
        double sqm = -((mx * mx + my * my) + mz * mz);
        v = (sqnd + 2.0 * dot) + sqm;
        oid = sg;
    } else {
        v = -1.0e300; oid = (1 << 28) + lane;
    }
#pragma unroll
    for (int k = 2; k <= 64; k <<= 1) {
#pragma unroll
        for (int j = k >> 1; j >= 1; j >>= 1) {
            double ov = __shfl_xor(v, j);
            int oi = __shfl_xor(oid, j);
            bool amLow = (lane & j) == 0;
            bool asc = (lane & k) == 0;
            bool gt = (ov > v) || (ov == v && oi < oid);
            bool ga = gt != amLow;
            bool take = asc ? ga : !ga;
            if (take) { v = ov; oid = oi; }
        }
    }
    if (lane >= 32) idxout[((size_t)b * NPTS + n) * 32 + (63 - lane)] = oid;
}

// ---------------- feature transpose [B,64,N] -> bf16 [B,N,64] --------------
__global__ __launch_bounds__(256) void transpose_kernel(const float* __restrict__ feat,
                                                        unsigned short* __restrict__ fTb) {
    __shared__ float tile[64][65];
    int b = blockIdx.x / 32;
    int n0 = (blockIdx.x % 32) * 64;
    int t = threadIdx.x;
    int nt = t % 64, cg = t / 64;
    for (int cc = 0; cc < 16; cc++) {
        int c2 = cg * 16 + cc;
        tile[c2][nt] = feat[((size_t)b * 64 + c2) * NPTS + n0 + nt];
    }
    __syncthreads();
    int c2 = t % 64, ng = t / 64;
    for (int nn2 = 0; nn2 < 16; nn2++) {
        int n = ng * 16 + nn2;
        fTb[((size_t)b * NPTS + n0 + n) * 64 + c2] = f2bf(tile[c2][n]);
    }
}

// ---- weight prep: fold group-shuffle + MLP into WtT[oc][4096] bf16 --------
__global__ __launch_bounds__(256) void wprep2_kernel(
    const float* __restrict__ cw, const float* __restrict__ mlpw,
    const float* __restrict__ mb, const float* __restrict__ cb,
    unsigned short* __restrict__ WtT, float* __restrict__ cbw) {
    int oc = blockIdx.x;
    int t = threadIdx.x;
    for (int i = t; i < 2048; i += 256) {
        int f = i >> 5, col = i & 31;
        int r = (f % 24) * 4 + f / 24;
        WtT[(size_t)oc * KROW + i] = f2bf(cw[(size_t)oc * 3072 + r * 32 + col]);
    }
    for (int i = t; i < 2048; i += 256) {
        int j = i >> 5, col = i & 31;
        float s = 0.f;
        for (int o2 = 0; o2 < 32; o2++) {
            int f = 64 + o2;
            int r = (f % 24) * 4 + f / 24;
            s = fmaf(mlpw[o2 * 64 + j], cw[(size_t)oc * 3072 + r * 32 + col], s);
        }
        WtT[(size_t)oc * KROW + 2048 + i] = f2bf(s);
    }
    if (t == 0) {
        float s = cb[oc];
        for (int o2 = 0; o2 < 32; o2++) {
            int f = 64 + o2;
            int r = (f % 24) * 4 + f / 24;
            float rowsum = 0.f;
            for (int col = 0; col < 32; col++) rowsum += cw[(size_t)oc * 3072 + r * 32 + col];
            s = fmaf(mb[o2], rowsum, s);
        }
        cbw[oc] = s;
    }
}

__global__ void kprep_kernel(const float* __restrict__ ker, double* __restrict__ kerd) {
    int i = threadIdx.x;
    if (i < 96) kerd[i] = (double)ker[i];
}

// ------- per-point kernel v4: register p-transpose (readlane), two-pass G2,
//         NO overlapping LDS buffers, r5 packs/addressing ------------------
__global__ __launch_bounds__(256) void point2_kernel(
    const float* __restrict__ x, const unsigned short* __restrict__ fTb,
    const int* __restrict__ idx, const float* __restrict__ Bm,
    const double* __restrict__ kerd, unsigned short* __restrict__ Aof,
    int m_base, int m_count) {
    __shared__ __align__(16) unsigned short lds2[4 * 3840];  // 30720 B/block
    int t = threadIdx.x;
    int wv = t >> 6, l = t & 63;
    int k = l & 31, h = l >> 5;
    unsigned short* G2 = lds2 + wv * 3840;   // [64][40] bf16 (5120 B)
    unsigned short* PT = G2 + 2560;          // [32][40] bf16 (2560 B)
    int lr = l & 15, lq = l >> 4;
    // per-lane kernel-column constants (column c = k), loaded once
    double ck0 = kerd[k], ck1 = kerd[32 + k], ck2 = kerd[64 + k];
    int gw = blockIdx.x * 4 + wv;
    int nw = gridDim.x * 4;

    for (int mi = gw; mi < m_count; mi += nw) {
        int m = m_base + mi;
        int b = m >> 11;
        int ik = idx[(size_t)m * 32 + k];
        const float* xb = x + (size_t)b * 3 * NPTS;
        float nx0 = xb[ik], ny0 = xb[NPTS + ik], nz0 = xb[2 * NPTS + ik];
        // hoisted feature-gather loads (consumed after softmax)
        const unsigned short* fr = fTb + (((size_t)b * NPTS + ik) * 64 + h * 32);
        uint4 f0 = *(const uint4*)fr;
        uint4 f1 = *(const uint4*)(fr + 8);
        uint4 f2 = *(const uint4*)(fr + 16);
        uint4 f3 = *(const uint4*)(fr + 24);

        float cx = __shfl(nx0, 0), cy = __shfl(ny0, 0), cz = __shfl(nz0, 0);
        double rxd = (double)nx0 - (double)cx;
        double ryd = (double)ny0 - (double)cy;
        double rzd = (double)nz0 - (double)cz;
        float rx = (float)rxd, ry = (float)ryd, rz = (float)rzd;
        float dist = sqrtf((rx * rx + ry * ry) + rz * rz);

        // p column c=k via readlane broadcast of each row's x_rel (registers only)
        double pd[32];
#pragma unroll
        for (int kk = 0; kk < 32; kk++) {
            double bx = bcast_d(rxd, kk);
            double by = bcast_d(ryd, kk);
            double bz = bcast_d(rzd, kk);
            pd[kk] = bx * ck0 + by * ck1 + bz * ck2;
        }
        if (k == 0) pd[0] += 1.0;   // one_pad at (row 0, col 0)

        // branchless fp64 top-3
        double m1 = -1.0e300, m2 = -1.0e300, m3 = -1.0e300;
#pragma unroll
        for (int kk = 0; kk < 32; kk++) {
            double v = pd[kk];
            double t2 = fmin(v, m1);
            double t3 = fmin(v, m2);
            m1 = fmax(m1, v);
            m2 = fmax(m2, t2);
            m3 = fmax(m3, t3);
        }
        // fp64-exact threshold, fp32 softmax
        float pv[32];
        float ssum = 0.f;
#pragma unroll
        for (int kk = 0; kk < 32; kk++) {
            float e = (pd[kk] >= m3) ? __expf((float)(pd[kk] - m1)) : 0.f;
            pv[kk] = e; ssum += e;
        }
        float rs = 1.f / ssum;
#pragma unroll
        for (int kk = 0; kk < 32; kk++) pv[kk] *= rs;

        // PT row c (k-contiguous bf16); h=0 writes k 0..15, h=1 k 16..31
        int c = k;
        {
            unsigned w[16];
#pragma unroll
            for (int i = 0; i < 16; i++)
                w[i] = (unsigned)f2bf(pv[2 * i]) | ((unsigned)f2bf(pv[2 * i + 1]) << 16);
            unsigned s[8];
#pragma unroll
            for (int i = 0; i < 8; i++) s[i] = h ? w[8 + i] : w[i];
            *(uint4*)&PT[c * 40 + h * 16]     = make_uint4(s[0], s[1], s[2], s[3]);
            *(uint4*)&PT[c * 40 + h * 16 + 8] = make_uint4(s[4], s[5], s[6], s[7]);
        }
        // G2 pass 1: gathered neighbor features rows 0..63, pair-pack across k
        {
            unsigned fw[16] = {f0.x, f0.y, f0.z, f0.w, f1.x, f1.y, f1.z, f1.w,
                               f2.x, f2.y, f2.z, f2.w, f3.x, f3.y, f3.z, f3.w};
#pragma unroll
            for (int c2 = 0; c2 < 16; c2++) {
                unsigned v = fw[c2];
                unsigned o = (unsigned)__shfl_xor((int)v, 1);
                unsigned wr = (k & 1) ? ((o >> 16) | (v & 0xFFFF0000u))
                                      : ((v & 0xFFFFu) | (o << 16));
                int ch = h * 32 + 2 * c2 + (k & 1);
                *(unsigned*)&G2[ch * 40 + (k & ~1)] = wr;
            }
        }
        asm volatile("" ::: "memory");

        // MFMA pass 1: O rows 0..63 (feats)
        bf16x8 af0 = *(const bf16x8*)&PT[(lr)      * 40 + lq * 8];
        bf16x8 af1 = *(const bf16x8*)&PT[(16 + lr) * 40 + lq * 8];
        size_t obase = (size_t)mi * KROW;
#pragma unroll
        for (int fb = 0; fb < 4; fb++) {
            int row = fb * 16 + lr;
            bf16x8 bfr = *(const bf16x8*)&G2[row * 40 + lq * 8];
            f32x4 d0 = __builtin_amdgcn_mfma_f32_16x16x32_bf16(af0, bfr, (f32x4){0.f, 0.f, 0.f, 0.f}, 0, 0, 0);
            f32x4 d1 = __builtin_amdgcn_mfma_f32_16x16x32_bf16(af1, bfr, (f32x4){0.f, 0.f, 0.f, 0.f}, 0, 0, 0);
            unsigned q0 = (unsigned)f2bf(d0.x) | ((unsigned)f2bf(d0.y) << 16);
            unsigned q1 = (unsigned)f2bf(d0.z) | ((unsigned)f2bf(d0.w) << 16);
            *(uint2*)&Aof[obase + row * 32 + lq * 4] = make_uint2(q0, q1);
            unsigned q2 = (unsigned)f2bf(d1.x) | ((unsigned)f2bf(d1.y) << 16);
            unsigned q3 = (unsigned)f2bf(d1.z) | ((unsigned)f2bf(d1.w) << 16);
            *(uint2*)&Aof[obase + row * 32 + 16 + lq * 4] = make_uint2(q2, q3);
        }
        asm volatile("" ::: "memory");

        // G2 pass 2: Fourier features rows 0..63 (sin 0..31, cos 32..63)
        {
            float u[32];
#pragma unroll
            for (int f = 0; f < 32; f++) {
                float uu = cx * Bm[f];
                uu = fmaf(cy, Bm[32 + f], uu);
                uu = fmaf(cz, Bm[64 + f], uu);
                uu = fmaf(rx, Bm[96 + f], uu);
                uu = fmaf(ry, Bm[128 + f], uu);
                uu = fmaf(rz, Bm[160 + f], uu);
                uu = fmaf(dist, Bm[192 + f], uu);
                u[f] = 6.28318530717958647692f * uu;
            }
            float tv[32];
            if (h == 0) {
#pragma unroll
                for (int f = 0; f < 32; f++) tv[f] = __sinf(u[f]);
            } else {
#pragma unroll
                for (int f = 0; f < 32; f++) tv[f] = __cosf(u[f]);
            }
#pragma unroll
            for (int jj = 0; jj < 16; jj++) {
                unsigned b0 = f2bf(tv[jj]), b1 = f2bf(tv[jj + 16]);
                unsigned o0 = (unsigned)__shfl_xor((int)b0, 1);
                unsigned o1 = (unsigned)__shfl_xor((int)b1, 1);
                unsigned wr = (k & 1) ? ((o1 & 0xFFFFu) | (b1 << 16))
                                      : ((b0 & 0xFFFFu) | (o0 << 16));
                int row = h * 32 + (k & 1) * 16 + jj;
                *(unsigned*)&G2[row * 40 + (k & ~1)] = wr;
            }
        }
        asm volatile("" ::: "memory");

        // MFMA pass 2: O rows 64..127
#pragma unroll
        for (int fb = 0; fb < 4; fb++) {
            int row = fb * 16 + lr;
            bf16x8 bfr = *(const bf16x8*)&G2[row * 40 + lq * 8];
            f32x4 d0 = __builtin_amdgcn_mfma_f32_16x16x32_bf16(af0, bfr, (f32x4){0.f, 0.f, 0.f, 0.f}, 0, 0, 0);
            f32x4 d1 = __builtin_amdgcn_mfma_f32_16x16x32_bf16(af1, bfr, (f32x4){0.f, 0.f, 0.f, 0.f}, 0, 0, 0);
            int f = 64 + row;
            unsigned q0 = (unsigned)f2bf(d0.x) | ((unsigned)f2bf(d0.y) << 16);
            unsigned q1 = (unsigned)f2bf(d0.z) | ((unsigned)f2bf(d0.w) << 16);
            *(uint2*)&Aof[obase + f * 32 + lq * 4] = make_uint2(q0, q1);
            unsigned q2 = (unsigned)f2bf(d1.x) | ((unsigned)f2bf(d1.y) << 16);
            unsigned q3 = (unsigned)f2bf(d1.z) | ((unsigned)f2bf(d1.w) << 16);
            *(uint2*)&Aof[obase + f * 32 + 16 + lq * 4] = make_uint2(q2, q3);
        }
        asm volatile("" ::: "memory");
    }
}

// ---------------- conv GEMM (MFMA): out = Aof[CSx4096] * Wtot --------------
__global__ __launch_bounds__(256) void conv2_kernel(
    const unsigned short* __restrict__ A, const unsigned short* __restrict__ WtT,
    const float* __restrict__ cbw, float* __restrict__ outp, int m_base) {
    __shared__ unsigned short Al[64 * 72];
    __shared__ unsigned short Wl[64 * 72];
    int t = threadIdx.x;
    int wv = t >> 6, l = t & 63;
    int lr = l & 15, lq = l >> 4;
    int m0 = blockIdx.x * 64;
    int mr = t >> 3, kq = t & 7;
    f32x4 acc[4] = {};
    for (int ks = 0; ks < 64; ks++) {
        int k0 = ks * 64;
        uint4 a0 = *(const uint4*)&A[(size_t)(m0 + mr) * KROW + k0 + kq * 8];
        uint4 a1 = *(const uint4*)&A[(size_t)(m0 + mr + 32) * KROW + k0 + kq * 8];
        uint4 w0 = *(const uint4*)&WtT[(size_t)mr * KROW + k0 + kq * 8];
        uint4 w1 = *(const uint4*)&WtT[(size_t)(mr + 32) * KROW + k0 + kq * 8];
        __syncthreads();
        *(uint4*)&Al[mr * 72 + kq * 8] = a0;
        *(uint4*)&Al[(mr + 32) * 72 + kq * 8] = a1;
        *(uint4*)&Wl[mr * 72 + kq * 8] = w0;
        *(uint4*)&Wl[(mr + 32) * 72 + kq * 8] = w1;
        __syncthreads();
#pragma unroll
        for (int kk = 0; kk < 2; kk++) {
            bf16x8 af = *(const bf16x8*)&Al[(wv * 16 + lr) * 72 + kk * 32 + lq * 8];
#pragma unroll
            for (int ocb = 0; ocb < 4; ocb++) {
                bf16x8 wf = *(const bf16x8*)&Wl[(ocb * 16 + lr) * 72 + kk * 32 + lq * 8];
                acc[ocb] = __builtin_amdgcn_mfma_f32_16x16x32_bf16(af, wf, acc[ocb], 0, 0, 0);
            }
        }
    }
    int m = m_base + m0 + wv * 16 + lq * 4;
    int b = m >> 11, n = m & 2047;
#pragma unroll
    for (int ocb = 0; ocb < 4; ocb++) {
        int oc = ocb * 16 + lr;
        float bias = cbw[oc];
        float4 v = make_float4(acc[ocb].x + bias, acc[ocb].y + bias,
                               acc[ocb].z + bias, acc[ocb].w + bias);
        *(float4*)&outp[((size_t)(b * 64 + oc)) * 2048 + n] = v;
    }
}

// ---------------- BatchNorm -----------------------------------------------
__global__ __launch_bounds__(256) void bn1_kernel(const float* __restrict__ outp,
                                                  float* __restrict__ sums) {
    int c = blockIdx.x, t = threadIdx.x;
    float s = 0.0f, s2 = 0.0f;
    for (int b = 0; b < NBATCH; b++) {
        const float* p = outp + ((size_t)b * 64 + c) * NPTS;
        for (int i = t; i < NPTS; i += 256) {
            float v = p[i];
            s += v; s2 = fmaf(v, v, s2);
        }
    }
    __shared__ float r1[256], r2[256];
    r1[t] = s; r2[t] = s2;
    __syncthreads();
    for (int st = 128; st > 0; st >>= 1) {
        if (t < st) { r1[t] += r1[t + st]; r2[t] += r2[t + st]; }
        __syncthreads();
    }
    if (t == 0) { sums[c] = r1[0]; sums[64 + c] = r2[0]; }
}

__global__ __launch_bounds__(256) void bn2_kernel(float* __restrict__ outp,
                                                  const float* __restrict__ sums,
                                                  const float* __restrict__ gamma,
                                                  const float* __restrict__ beta) {
    int i = blockIdx.x * 256 + threadIdx.x;
    if (i >= MTOT * 64) return;
    int c = (i >> 11) & 63;
    float mean = sums[c] * (1.0f / (float)MTOT);
    float var = sums[64 + c] * (1.0f / (float)MTOT) - mean * mean;
    float inv = rsqrtf(var + 1e-5f);
    outp[i] = fmaf(gamma[c], (outp[i] - mean) * inv, beta[c]);
}

extern "C" void kernel_launch(void* const* d_in, const int* in_sizes, int n_in,
                              void* d_out, int out_size, void* d_ws, size_t ws_size,
                              hipStream_t stream) {
    (void)in_sizes; (void)n_in; (void)out_size;
    const float* x    = (const float*)d_in[0];
    const float* fea  = (const float*)d_in[1];
    const float* Bm   = (const float*)d_in[2];
    const float* ker  = (const float*)d_in[3];
    const float* mw   = (const float*)d_in[4];
    const float* mb   = (const float*)d_in[5];
    const float* cw   = (const float*)d_in[6];
    const float* cb   = (const float*)d_in[7];
    const float* gam  = (const float*)d_in[8];
    const float* bet  = (const float*)d_in[9];
    float* outp = (float*)d_out;

    char* wsb = (char*)d_ws;
    size_t off = 0;
    auto carve = [&](size_t sz) {
        void* p = wsb + off;
        off = (off + sz + 255) & ~(size_t)255;
        return p;
    };
    unsigned short* fTb  = (unsigned short*)carve((size_t)MTOT * 64 * 2);
    int*            idxw = (int*)carve((size_t)MTOT * 32 * 4);
    unsigned short* WtT  = (unsigned short*)carve((size_t)OUTC * KROW * 2);
    float*          cbw  = (float*)carve(64 * 4);
    double*         kerd = (double*)carve(96 * 8);
    float*          sums = (float*)carve(2 * 64 * 4);
    size_t fixedEnd = off;
    int CS = 16384;
    while (fixedEnd + (size_t)CS * KROW * 2 > ws_size && CS > 2048) CS >>= 1;
    unsigned short* Aof = (unsigned short*)(wsb + fixedEnd);

    knn_kernel<<<NBATCH * (NPTS / 4), 256, 0, stream>>>(x, idxw);
    transpose_kernel<<<NBATCH * 32, 256, 0, stream>>>(fea, fTb);
    wprep2_kernel<<<64, 256, 0, stream>>>(cw, mw, mb, cb, WtT, cbw);
    kprep_kernel<<<1, 128, 0, stream>>>(ker, kerd);

    for (int c0 = 0; c0 < MTOT; c0 += CS) {
        point2_kernel<<<1024, 256, 0, stream>>>(x, fTb, idxw, Bm, kerd, Aof, c0, CS);
        conv2_kernel<<<CS / 64, 256, 0, stream>>>(Aof, WtT, cbw, outp, c0);
    }
    bn1_kernel<<<64, 256, 0, stream>>>(outp, sums);
    bn2_kernel<<<(MTOT * 64 + 255) / 256, 256, 0, stream>>>(outp, sums, gam, bet);
}

// Round 8
// 211.741 us; speedup vs baseline: 3.8909x; 1.0305x over previous
//
#include <hip/hip_runtime.h>
#include <math.h>

#define NPTS 2048
#define NBATCH 8
#define MTOT (NBATCH*NPTS)
#define KROW 4096   // conv K: 128 rows * 32 cols
#define OUTC 64

using bf16x8 = __attribute__((ext_vector_type(8))) short;
using f32x4  = __attribute__((ext_vector_type(4))) float;

__device__ __forceinline__ unsigned short f2bf(float f) {
    unsigned u = __float_as_uint(f);
    unsigned r = u + 0x7FFFu + ((u >> 16) & 1u);
    return (unsigned short)(r >> 16);
}

__device__ __forceinline__ unsigned wave_max_u32(unsigned v) {
    int x = (int)v, t;
    t = __builtin_amdgcn_update_dpp(x, x, 0x111, 0xF, 0xF, false); x = ((unsigned)t > (unsigned)x) ? t : x;
    t = __builtin_amdgcn_update_dpp(x, x, 0x112, 0xF, 0xF, false); x = ((unsigned)t > (unsigned)x) ? t : x;
    t = __builtin_amdgcn_update_dpp(x, x, 0x114, 0xF, 0xF, false); x = ((unsigned)t > (unsigned)x) ? t : x;
    t = __builtin_amdgcn_update_dpp(x, x, 0x118, 0xF, 0xF, false); x = ((unsigned)t > (unsigned)x) ? t : x;
    t = __builtin_amdgcn_update_dpp(x, x, 0x142, 0xa, 0xF, false); x = ((unsigned)t > (unsigned)x) ? t : x;
    t = __builtin_amdgcn_update_dpp(x, x, 0x143, 0xc, 0xF, false); x = ((unsigned)t > (unsigned)x) ? t : x;
    return (unsigned)__builtin_amdgcn_readlane(x, 63);
}

// ---- KNN: fp32 tournament prefilter (top-40) + fp64 exact re-rank --------
__global__ __launch_bounds__(256) void knn_kernel(const float* __restrict__ x,
                                                  int* __restrict__ idxout) {
    __shared__ float xs[NPTS], ys[NPTS], zs[NPTS], sqs[NPTS];
    int t = threadIdx.x;
    int b = blockIdx.x / (NPTS / 4);
    int grp = blockIdx.x % (NPTS / 4);
    const float* xb = x + (size_t)b * 3 * NPTS;
    for (int i = t; i < NPTS; i += 256) {
        float vx = xb[i], vy = xb[NPTS + i], vz = xb[2 * NPTS + i];
        xs[i] = vx; ys[i] = vy; zs[i] = vz;
        sqs[i] = -((vx * vx + vy * vy) + vz * vz);
    }
    __syncthreads();
    int wave = t >> 6, lane = t & 63;
    int n = grp * 4 + wave;
    float cx = xs[n], cy = ys[n], cz = zs[n];
    float sqn = sqs[n];
    float cx2 = 2.0f * cx, cy2 = 2.0f * cy, cz2 = 2.0f * cz;

    unsigned key[32];
#pragma unroll
    for (int j = 0; j < 32; j++) {
        int cand = j * 64 + lane;
        float v = sqn + sqs[cand];
        v = fmaf(cx2, xs[cand], v);
        v = fmaf(cy2, ys[cand], v);
        v = fmaf(cz2, zs[cand], v);
        unsigned u = __float_as_uint(v);
        unsigned ord = u ^ ((u >> 31) ? 0xFFFFFFFFu : 0x80000000u);
        key[j] = (ord & 0xFFFFFFE0u) | (unsigned)j;
    }
#pragma unroll
    for (int k = 2; k <= 32; k <<= 1) {
#pragma unroll
        for (int j = k >> 1; j >= 1; j >>= 1) {
#pragma unroll
            for (int i = 0; i < 32; i++) {
                int l2 = i ^ j;
                if (l2 > i) {
                    unsigned a = key[i], bb = key[l2];
                    unsigned hi = a > bb ? a : bb, lo = a > bb ? bb : a;
                    if ((i & k) == 0) { key[i] = hi; key[l2] = lo; }
                    else              { key[i] = lo; key[l2] = hi; }
                }
            }
        }
    }
    int sg = 0;
    for (int r = 0; r < 40; r++) {
        unsigned m = wave_max_u32(key[0]);
        unsigned long long ball = __ballot(key[0] == m);
        int bl = __ffsll(ball) - 1;
        int gidx = (int)(m & 31u) * 64 + bl;
        if (lane == r) sg = gidx;
        bool won = (lane == bl);
#pragma unroll
        for (int i = 0; i < 11; i++) key[i] = won ? key[i + 1] : key[i];
        key[11] = won ? 0u : key[11];
    }
    double cxd = (double)cx, cyd = (double)cy, czd = (double)cz;
    double sqnd = -((cxd * cxd + cyd * cyd) + czd * czd);
    double v; int oid;
    if (lane < 40) {
        double mx = (double)xs[sg], my = (double)ys[sg], mz = (double)zs[sg];
        double dot = (cxd * mx + cyd * my) + czd * mz;
        double sqm = -((mx * mx + my * my) + mz * mz);
        v = (sqnd + 2.0 * dot) + sqm;
        oid = sg;
    } else {
        v = -1.0e300; oid = (1 << 28) + lane;
    }
#pragma unroll
    for (int k = 2; k <= 64; k <<= 1) {
#pragma unroll
        for (int j = k >> 1; j >= 1; j >>= 1) {
            double ov = __shfl_xor(v, j);
            int oi = __shfl_xor(oid, j);
            bool amLow = (lane & j) == 0;
            bool asc = (lane & k) == 0;
            bool gt = (ov > v) || (ov == v && oi < oid);
            bool ga = gt != amLow;
            bool take = asc ? ga : !ga;
            if (take) { v = ov; oid = oi; }
        }
    }
    if (lane >= 32) idxout[((size_t)b * NPTS + n) * 32 + (63 - lane)] = oid;
}

// ---------------- feature transpose [B,64,N] -> bf16 [B,N,64] --------------
__global__ __launch_bounds__(256) void transpose_kernel(const float* __restrict__ feat,
                                                        unsigned short* __restrict__ fTb) {
    __shared__ float tile[64][65];
    int b = blockIdx.x / 32;
    int n0 = (blockIdx.x % 32) * 64;
    int t = threadIdx.x;
    int nt = t % 64, cg = t / 64;
    for (int cc = 0; cc < 16; cc++) {
        int c2 = cg * 16 + cc;
        tile[c2][nt] = feat[((size_t)b * 64 + c2) * NPTS + n0 + nt];
    }
    __syncthreads();
    int c2 = t % 64, ng = t / 64;
    for (int nn2 = 0; nn2 < 16; nn2++) {
        int n = ng * 16 + nn2;
        fTb[((size_t)b * NPTS + n0 + n) * 64 + c2] = f2bf(tile[c2][n]);
    }
}

// ---- weight prep: fold group-shuffle + MLP into WtT[oc][4096] bf16 --------
__global__ __launch_bounds__(256) void wprep2_kernel(
    const float* __restrict__ cw, const float* __restrict__ mlpw,
    const float* __restrict__ mb, const float* __restrict__ cb,
    unsigned short* __restrict__ WtT, float* __restrict__ cbw) {
    int oc = blockIdx.x;
    int t = threadIdx.x;
    for (int i = t; i < 2048; i += 256) {
        int f = i >> 5, col = i & 31;
        int r = (f % 24) * 4 + f / 24;
        WtT[(size_t)oc * KROW + i] = f2bf(cw[(size_t)oc * 3072 + r * 32 + col]);
    }
    for (int i = t; i < 2048; i += 256) {
        int j = i >> 5, col = i & 31;
        float s = 0.f;
        for (int o2 = 0; o2 < 32; o2++) {
            int f = 64 + o2;
            int r = (f % 24) * 4 + f / 24;
            s = fmaf(mlpw[o2 * 64 + j], cw[(size_t)oc * 3072 + r * 32 + col], s);
        }
        WtT[(size_t)oc * KROW + 2048 + i] = f2bf(s);
    }
    if (t == 0) {
        float s = cb[oc];
        for (int o2 = 0; o2 < 32; o2++) {
            int f = 64 + o2;
            int r = (f % 24) * 4 + f / 24;
            float rowsum = 0.f;
            for (int col = 0; col < 32; col++) rowsum += cw[(size_t)oc * 3072 + r * 32 + col];
            s = fmaf(mb[o2], rowsum, s);
        }
        cbw[oc] = s;
    }
}

__global__ void kprep_kernel(const float* __restrict__ ker, double* __restrict__ kerd) {
    int i = threadIdx.x;
    if (i < 96) kerd[i] = (double)ker[i];
}

// ---- perm kernel: 2 points/wave; fp64 p + top3 + softmax -> PTws bf16 ----
__global__ __launch_bounds__(256) void perm_kernel(
    const float* __restrict__ x, const int* __restrict__ idx,
    const double* __restrict__ kerd, unsigned short* __restrict__ PTws) {
    int t = threadIdx.x;
    int wv = t >> 6, l = t & 63;
    int c = l & 31;
    int cbase = l & 32;               // 0 for point A lanes, 32 for point B lanes
    int m = blockIdx.x * 8 + wv * 2 + (l >> 5);
    int b = m >> 11;
    int ik = idx[(size_t)m * 32 + c];
    const float* xb = x + (size_t)b * 3 * NPTS;
    float nx0 = xb[ik], ny0 = xb[NPTS + ik], nz0 = xb[2 * NPTS + ik];
    float cx = __shfl(nx0, cbase), cy = __shfl(ny0, cbase), cz = __shfl(nz0, cbase);
    double rxd = (double)nx0 - (double)cx;
    double ryd = (double)ny0 - (double)cy;
    double rzd = (double)nz0 - (double)cz;
    double ck0 = kerd[c], ck1 = kerd[32 + c], ck2 = kerd[64 + c];

    // p column c of own point: row kk's x_rel broadcast from lane cbase+kk
    double pd[32];
#pragma unroll
    for (int kk = 0; kk < 32; kk++) {
        double bx = __shfl(rxd, cbase + kk);
        double by = __shfl(ryd, cbase + kk);
        double bz = __shfl(rzd, cbase + kk);
        pd[kk] = bx * ck0 + by * ck1 + bz * ck2;
    }
    if (c == 0) pd[0] += 1.0;   // one_pad at (row 0, col 0), per point

    // branchless fp64 top-3
    double m1 = -1.0e300, m2 = -1.0e300, m3 = -1.0e300;
#pragma unroll
    for (int kk = 0; kk < 32; kk++) {
        double v = pd[kk];
        double t2 = fmin(v, m1);
        double t3 = fmin(v, m2);
        m1 = fmax(m1, v);
        m2 = fmax(m2, t2);
        m3 = fmax(m3, t3);
    }
    // fp64-exact threshold, fp32 softmax
    float pv[32];
    float ssum = 0.f;
#pragma unroll
    for (int kk = 0; kk < 32; kk++) {
        float e = (pd[kk] >= m3) ? __expf((float)(pd[kk] - m1)) : 0.f;
        pv[kk] = e; ssum += e;
    }
    float rs = 1.f / ssum;
#pragma unroll
    for (int kk = 0; kk < 32; kk++) pv[kk] *= rs;

    // pack row c (k-contiguous bf16) and store to PTws[m][c][0..31]
    unsigned w[16];
#pragma unroll
    for (int i = 0; i < 16; i++)
        w[i] = (unsigned)f2bf(pv[2 * i]) | ((unsigned)f2bf(pv[2 * i + 1]) << 16);
    size_t obase = (size_t)m * 1024 + (size_t)c * 32;
    *(uint4*)&PTws[obase]      = make_uint4(w[0], w[1], w[2], w[3]);
    *(uint4*)&PTws[obase + 8]  = make_uint4(w[4], w[5], w[6], w[7]);
    *(uint4*)&PTws[obase + 16] = make_uint4(w[8], w[9], w[10], w[11]);
    *(uint4*)&PTws[obase + 24] = make_uint4(w[12], w[13], w[14], w[15]);
}

// ------- point3: gather + fourier + O=G*perm (MFMA); perm from PTws -------
__global__ __launch_bounds__(256) void point3_kernel(
    const float* __restrict__ x, const unsigned short* __restrict__ fTb,
    const int* __restrict__ idx, const float* __restrict__ Bm,
    const unsigned short* __restrict__ PTws, unsigned short* __restrict__ Aof,
    int m_base, int m_count) {
    __shared__ __align__(16) unsigned short lds2[4 * 2560];  // G2 only: 20480 B/block
    int t = threadIdx.x;
    int wv = t >> 6, l = t & 63;
    int k = l & 31, h = l >> 5;
    unsigned short* G2 = lds2 + wv * 2560;   // [64][40] bf16 (5120 B)
    int lr = l & 15, lq = l >> 4;
    int gw = blockIdx.x * 4 + wv;
    int nw = gridDim.x * 4;

    for (int mi = gw; mi < m_count; mi += nw) {
        int m = m_base + mi;
        int b = m >> 11;
        int ik = idx[(size_t)m * 32 + k];
        const float* xb = x + (size_t)b * 3 * NPTS;
        float nx0 = xb[ik], ny0 = xb[NPTS + ik], nz0 = xb[2 * NPTS + ik];
        // hoisted loads: features + perm fragments
        const unsigned short* fr = fTb + (((size_t)b * NPTS + ik) * 64 + h * 32);
        uint4 f0 = *(const uint4*)fr;
        uint4 f1 = *(const uint4*)(fr + 8);
        uint4 f2 = *(const uint4*)(fr + 16);
        uint4 f3 = *(const uint4*)(fr + 24);
        const unsigned short* ptp = PTws + (size_t)m * 1024;
        bf16x8 af0 = *(const bf16x8*)&ptp[lr * 32 + lq * 8];
        bf16x8 af1 = *(const bf16x8*)&ptp[(16 + lr) * 32 + lq * 8];

        float cx = __shfl(nx0, 0), cy = __shfl(ny0, 0), cz = __shfl(nz0, 0);
        float rx = nx0 - cx, ry = ny0 - cy, rz = nz0 - cz;
        float dist = sqrtf((rx * rx + ry * ry) + rz * rz);

        // G2 pass 1: gathered neighbor features rows 0..63, pair-pack across k
        {
            unsigned fw[16] = {f0.x, f0.y, f0.z, f0.w, f1.x, f1.y, f1.z, f1.w,
                               f2.x, f2.y, f2.z, f2.w, f3.x, f3.y, f3.z, f3.w};
#pragma unroll
            for (int c2 = 0; c2 < 16; c2++) {
                unsigned v = fw[c2];
                unsigned o = (unsigned)__shfl_xor((int)v, 1);
                unsigned wr = (k & 1) ? ((o >> 16) | (v & 0xFFFF0000u))
                                      : ((v & 0xFFFFu) | (o << 16));
                int ch = h * 32 + 2 * c2 + (k & 1);
                *(unsigned*)&G2[ch * 40 + (k & ~1)] = wr;
            }
        }
        asm volatile("" ::: "memory");

        // MFMA pass 1: O rows 0..63 (feats)
        size_t obase = (size_t)mi * KROW;
#pragma unroll
        for (int fb = 0; fb < 4; fb++) {
            int row = fb * 16 + lr;
            bf16x8 bfr = *(const bf16x8*)&G2[row * 40 + lq * 8];
            f32x4 d0 = __builtin_amdgcn_mfma_f32_16x16x32_bf16(af0, bfr, (f32x4){0.f, 0.f, 0.f, 0.f}, 0, 0, 0);
            f32x4 d1 = __builtin_amdgcn_mfma_f32_16x16x32_bf16(af1, bfr, (f32x4){0.f, 0.f, 0.f, 0.f}, 0, 0, 0);
            unsigned q0 = (unsigned)f2bf(d0.x) | ((unsigned)f2bf(d0.y) << 16);
            unsigned q1 = (unsigned)f2bf(d0.z) | ((unsigned)f2bf(d0.w) << 16);
            *(uint2*)&Aof[obase + row * 32 + lq * 4] = make_uint2(q0, q1);
            unsigned q2 = (unsigned)f2bf(d1.x) | ((unsigned)f2bf(d1.y) << 16);
            unsigned q3 = (unsigned)f2bf(d1.z) | ((unsigned)f2bf(d1.w) << 16);
            *(uint2*)&Aof[obase + row * 32 + 16 + lq * 4] = make_uint2(q2, q3);
        }
        asm volatile("" ::: "memory");

        // G2 pass 2: Fourier features rows 0..63 (sin 0..31, cos 32..63)
        {
            float u[32];
#pragma unroll
            for (int f = 0; f < 32; f++) {
                float uu = cx * Bm[f];
                uu = fmaf(cy, Bm[32 + f], uu);
                uu = fmaf(cz, Bm[64 + f], uu);
                uu = fmaf(rx, Bm[96 + f], uu);
                uu = fmaf(ry, Bm[128 + f], uu);
                uu = fmaf(rz, Bm[160 + f], uu);
                uu = fmaf(dist, Bm[192 + f], uu);
                u[f] = 6.28318530717958647692f * uu;
            }
            float tv[32];
            if (h == 0) {
#pragma unroll
                for (int f = 0; f < 32; f++) tv[f] = __sinf(u[f]);
            } else {
#pragma unroll
                for (int f = 0; f < 32; f++) tv[f] = __cosf(u[f]);
            }
#pragma unroll
            for (int jj = 0; jj < 16; jj++) {
                unsigned b0 = f2bf(tv[jj]), b1 = f2bf(tv[jj + 16]);
                unsigned o0 = (unsigned)__shfl_xor((int)b0, 1);
                unsigned o1 = (unsigned)__shfl_xor((int)b1, 1);
                unsigned wr = (k & 1) ? ((o1 & 0xFFFFu) | (b1 << 16))
                                      : ((b0 & 0xFFFFu) | (o0 << 16));
                int row = h * 32 + (k & 1) * 16 + jj;
                *(unsigned*)&G2[row * 40 + (k & ~1)] = wr;
            }
        }
        asm volatile("" ::: "memory");

        // MFMA pass 2: O rows 64..127
#pragma unroll
        for (int fb = 0; fb < 4; fb++) {
            int row = fb * 16 + lr;
            bf16x8 bfr = *(const bf16x8*)&G2[row * 40 + lq * 8];
            f32x4 d0 = __builtin_amdgcn_mfma_f32_16x16x32_bf16(af0, bfr, (f32x4){0.f, 0.f, 0.f, 0.f}, 0, 0, 0);
            f32x4 d1 = __builtin_amdgcn_mfma_f32_16x16x32_bf16(af1, bfr, (f32x4){0.f, 0.f, 0.f, 0.f}, 0, 0, 0);
            int f = 64 + row;
            unsigned q0 = (unsigned)f2bf(d0.x) | ((unsigned)f2bf(d0.y) << 16);
            unsigned q1 = (unsigned)f2bf(d0.z) | ((unsigned)f2bf(d0.w) << 16);
            *(uint2*)&Aof[obase + f * 32 + lq * 4] = make_uint2(q0, q1);
            unsigned q2 = (unsigned)f2bf(d1.x) | ((unsigned)f2bf(d1.y) << 16);
            unsigned q3 = (unsigned)f2bf(d1.z) | ((unsigned)f2bf(d1.w) << 16);
            *(uint2*)&Aof[obase + f * 32 + 16 + lq * 4] = make_uint2(q2, q3);
        }
        asm volatile("" ::: "memory");
    }
}

// ---------------- conv GEMM (MFMA): out = Aof[CSx4096] * Wtot --------------
__global__ __launch_bounds__(256) void conv2_kernel(
    const unsigned short* __restrict__ A, const unsigned short* __restrict__ WtT,
    const float* __restrict__ cbw, float* __restrict__ outp, int m_base) {
    __shared__ unsigned short Al[64 * 72];
    __shared__ unsigned short Wl[64 * 72];
    int t = threadIdx.x;
    int wv = t >> 6, l = t & 63;
    int lr = l & 15, lq = l >> 4;
    int m0 = blockIdx.x * 64;
    int mr = t >> 3, kq = t & 7;
    f32x4 acc[4] = {};
    for (int ks = 0; ks < 64; ks++) {
        int k0 = ks * 64;
        uint4 a0 = *(const uint4*)&A[(size_t)(m0 + mr) * KROW + k0 + kq * 8];
        uint4 a1 = *(const uint4*)&A[(size_t)(m0 + mr + 32) * KROW + k0 + kq * 8];
        uint4 w0 = *(const uint4*)&WtT[(size_t)mr * KROW + k0 + kq * 8];
        uint4 w1 = *(const uint4*)&WtT[(size_t)(mr + 32) * KROW + k0 + kq * 8];
        __syncthreads();
        *(uint4*)&Al[mr * 72 + kq * 8] = a0;
        *(uint4*)&Al[(mr + 32) * 72 + kq * 8] = a1;
        *(uint4*)&Wl[mr * 72 + kq * 8] = w0;
        *(uint4*)&Wl[(mr + 32) * 72 + kq * 8] = w1;
        __syncthreads();
#pragma unroll
        for (int kk = 0; kk < 2; kk++) {
            bf16x8 af = *(const bf16x8*)&Al[(wv * 16 + lr) * 72 + kk * 32 + lq * 8];
#pragma unroll
            for (int ocb = 0; ocb < 4; ocb++) {
                bf16x8 wf = *(const bf16x8*)&Wl[(ocb * 16 + lr) * 72 + kk * 32 + lq * 8];
                acc[ocb] = __builtin_amdgcn_mfma_f32_16x16x32_bf16(af, wf, acc[ocb], 0, 0, 0);
            }
        }
    }
    int m = m_base + m0 + wv * 16 + lq * 4;
    int b = m >> 11, n = m & 2047;
#pragma unroll
    for (int ocb = 0; ocb < 4; ocb++) {
        int oc = ocb * 16 + lr;
        float bias = cbw[oc];
        float4 v = make_float4(acc[ocb].x + bias, acc[ocb].y + bias,
                               acc[ocb].z + bias, acc[ocb].w + bias);
        *(float4*)&outp[((size_t)(b * 64 + oc)) * 2048 + n] = v;
    }
}

// ---------------- BatchNorm -----------------------------------------------
__global__ __launch_bounds__(256) void bn1_kernel(const float* __restrict__ outp,
                                                  float* __restrict__ sums) {
    int c = blockIdx.x, t = threadIdx.x;
    float s = 0.0f, s2 = 0.0f;
    for (int b = 0; b < NBATCH; b++) {
        const float* p = outp + ((size_t)b * 64 + c) * NPTS;
        for (int i = t; i < NPTS; i += 256) {
            float v = p[i];
            s += v; s2 = fmaf(v, v, s2);
        }
    }
    __shared__ float r1[256], r2[256];
    r1[t] = s; r2[t] = s2;
    __syncthreads();
    for (int st = 128; st > 0; st >>= 1) {
        if (t < st) { r1[t] += r1[t + st]; r2[t] += r2[t + st]; }
        __syncthreads();
    }
    if (t == 0) { sums[c] = r1[0]; sums[64 + c] = r2[0]; }
}

__global__ __launch_bounds__(256) void bn2_kernel(float* __restrict__ outp,
                                                  const float* __restrict__ sums,
                                                  const float* __restrict__ gamma,
                                                  const float* __restrict__ beta) {
    int i = blockIdx.x * 256 + threadIdx.x;
    if (i >= MTOT * 64) return;
    int c = (i >> 11) & 63;
    float mean = sums[c] * (1.0f / (float)MTOT);
    float var = sums[64 + c] * (1.0f / (float)MTOT) - mean * mean;
    float inv = rsqrtf(var + 1e-5f);
    outp[i] = fmaf(gamma[c], (outp[i] - mean) * inv, beta[c]);
}

extern "C" void kernel_launch(void* const* d_in, const int* in_sizes, int n_in,
                              void* d_out, int out_size, void* d_ws, size_t ws_size,
                              hipStream_t stream) {
    (void)in_sizes; (void)n_in; (void)out_size;
    const float* x    = (const float*)d_in[0];
    const float* fea  = (const float*)d_in[1];
    const float* Bm   = (const float*)d_in[2];
    const float* ker  = (const float*)d_in[3];
    const float* mw   = (const float*)d_in[4];
    const float* mb   = (const float*)d_in[5];
    const float* cw   = (const float*)d_in[6];
    const float* cb   = (const float*)d_in[7];
    const float* gam  = (const float*)d_in[8];
    const float* bet  = (const float*)d_in[9];
    float* outp = (float*)d_out;

    char* wsb = (char*)d_ws;
    size_t off = 0;
    auto carve = [&](size_t sz) {
        void* p = wsb + off;
        off = (off + sz + 255) & ~(size_t)255;
        return p;
    };
    unsigned short* fTb  = (unsigned short*)carve((size_t)MTOT * 64 * 2);
    int*            idxw = (int*)carve((size_t)MTOT * 32 * 4);
    unsigned short* WtT  = (unsigned short*)carve((size_t)OUTC * KROW * 2);
    float*          cbw  = (float*)carve(64 * 4);
    double*         kerd = (double*)carve(96 * 8);
    float*          sums = (float*)carve(2 * 64 * 4);
    unsigned short* PTws = (unsigned short*)carve((size_t)MTOT * 1024 * 2);  // 32 MB
    size_t fixedEnd = off;
    int CS = 16384;
    while (fixedEnd + (size_t)CS * KROW * 2 > ws_size && CS > 2048) CS >>= 1;
    unsigned short* Aof = (unsigned short*)(wsb + fixedEnd);

    knn_kernel<<<NBATCH * (NPTS / 4), 256, 0, stream>>>(x, idxw);
    transpose_kernel<<<NBATCH * 32, 256, 0, stream>>>(fea, fTb);
    wprep2_kernel<<<64, 256, 0, stream>>>(cw, mw, mb, cb, WtT, cbw);
    kprep_kernel<<<1, 128, 0, stream>>>(ker, kerd);
    perm_kernel<<<MTOT / 8, 256, 0, stream>>>(x, idxw, kerd, PTws);

    for (int c0 = 0; c0 < MTOT; c0 += CS) {
        point3_kernel<<<1536, 256, 0, stream>>>(x, fTb, idxw, Bm, PTws, Aof, c0, CS);
        conv2_kernel<<<CS / 64, 256, 0, stream>>>(Aof, WtT, cbw, outp, c0);
    }
    bn1_kernel<<<64, 256, 0, stream>>>(outp, sums);
    bn2_kernel<<<(MTOT * 64 + 255) / 256, 256, 0, stream>>>(outp, sums, gam, bet);
}

// Round 9
// 202.396 us; speedup vs baseline: 4.0705x; 1.0462x over previous
//
#include <hip/hip_runtime.h>
#include <hip/hip_bf16.h>
#include <math.h>

#define NPTS 2048
#define NBATCH 8
#define MTOT (NBATCH*NPTS)
#define KROW 4096   // conv K: 128 rows * 32 cols
#define OUTC 64

using bf16x8 = __attribute__((ext_vector_type(8))) short;
using f32x4  = __attribute__((ext_vector_type(4))) float;

__device__ __forceinline__ unsigned short f2bf(float f) {
    unsigned u = __float_as_uint(f);
    unsigned r = u + 0x7FFFu + ((u >> 16) & 1u);
    return (unsigned short)(r >> 16);
}
// pair-pack via compiler-fused v_cvt_pk_bf16_f32 (RNE, identical to f2bf)
__device__ __forceinline__ unsigned pk2bf(float lo, float hi) {
    __hip_bfloat162 h2 = __float22bfloat162_rn(make_float2(lo, hi));
    return *reinterpret_cast<unsigned*>(&h2);
}

__device__ __forceinline__ unsigned wave_max_u32(unsigned v) {
    int x = (int)v, t;
    t = __builtin_amdgcn_update_dpp(x, x, 0x111, 0xF, 0xF, false); x = ((unsigned)t > (unsigned)x) ? t : x;
    t = __builtin_amdgcn_update_dpp(x, x, 0x112, 0xF, 0xF, false); x = ((unsigned)t > (unsigned)x) ? t : x;
    t = __builtin_amdgcn_update_dpp(x, x, 0x114, 0xF, 0xF, false); x = ((unsigned)t > (unsigned)x) ? t : x;
    t = __builtin_amdgcn_update_dpp(x, x, 0x118, 0xF, 0xF, false); x = ((unsigned)t > (unsigned)x) ? t : x;
    t = __builtin_amdgcn_update_dpp(x, x, 0x142, 0xa, 0xF, false); x = ((unsigned)t > (unsigned)x) ? t : x;
    t = __builtin_amdgcn_update_dpp(x, x, 0x143, 0xc, 0xF, false); x = ((unsigned)t > (unsigned)x) ? t : x;
    return (unsigned)__builtin_amdgcn_readlane(x, 63);
}

// ---- KNN: fp32 tournament prefilter (top-40) + fp64 exact re-rank --------
// 512 threads = 8 waves = 8 points per block; coords packed float4 in LDS
__global__ __launch_bounds__(512) void knn_kernel(const float* __restrict__ x,
                                                  int* __restrict__ idxout) {
    __shared__ float4 ps[NPTS];   // (x, y, z, -|p|^2)  32 KB
    int t = threadIdx.x;
    int b = blockIdx.x / (NPTS / 8);
    int grp = blockIdx.x % (NPTS / 8);
    const float* xb = x + (size_t)b * 3 * NPTS;
    for (int i = t; i < NPTS; i += 512) {
        float vx = xb[i], vy = xb[NPTS + i], vz = xb[2 * NPTS + i];
        ps[i] = make_float4(vx, vy, vz, -((vx * vx + vy * vy) + vz * vz));
    }
    __syncthreads();
    int wave = t >> 6, lane = t & 63;
    int n = grp * 8 + wave;
    float4 pc = ps[n];
    float cx = pc.x, cy = pc.y, cz = pc.z;
    float sqn = pc.w;
    float cx2 = 2.0f * cx, cy2 = 2.0f * cy, cz2 = 2.0f * cz;

    unsigned key[32];
#pragma unroll
    for (int j = 0; j < 32; j++) {
        int cand = j * 64 + lane;
        float4 q = ps[cand];
        float v = sqn + q.w;
        v = fmaf(cx2, q.x, v);
        v = fmaf(cy2, q.y, v);
        v = fmaf(cz2, q.z, v);
        unsigned u = __float_as_uint(v);
        unsigned ord = u ^ ((u >> 31) ? 0xFFFFFFFFu : 0x80000000u);
        key[j] = (ord & 0xFFFFFFE0u) | (unsigned)j;
    }
#pragma unroll
    for (int k = 2; k <= 32; k <<= 1) {
#pragma unroll
        for (int j = k >> 1; j >= 1; j >>= 1) {
#pragma unroll
            for (int i = 0; i < 32; i++) {
                int l2 = i ^ j;
                if (l2 > i) {
                    unsigned a = key[i], bb = key[l2];
                    unsigned hi = a > bb ? a : bb, lo = a > bb ? bb : a;
                    if ((i & k) == 0) { key[i] = hi; key[l2] = lo; }
                    else              { key[i] = lo; key[l2] = hi; }
                }
            }
        }
    }
    int sg = 0;
    for (int r = 0; r < 40; r++) {
        unsigned m = wave_max_u32(key[0]);
        unsigned long long ball = __ballot(key[0] == m);
        int bl = __ffsll(ball) - 1;
        int gidx = (int)(m & 31u) * 64 + bl;
        if (lane == r) sg = gidx;
        bool won = (lane == bl);
#pragma unroll
        for (int i = 0; i < 11; i++) key[i] = won ? key[i + 1] : key[i];
        key[11] = won ? 0u : key[11];
    }
    double cxd = (double)cx, cyd = (double)cy, czd = (double)cz;
    double sqnd = -((cxd * cxd + cyd * cyd) + czd * czd);
    double v; int oid;
    if (lane < 40) {
        float4 qq = ps[sg];
        double mx = (double)qq.x, my = (double)qq.y, mz = (double)qq.z;
        double dot = (cxd * mx + cyd * my) + czd * mz;
        double sqm = -((mx * mx + my * my) + mz * mz);
        v = (sqnd + 2.0 * dot) + sqm;
        oid = sg;
    } else {
        v = -1.0e300; oid = (1 << 28) + lane;
    }
#pragma unroll
    for (int k = 2; k <= 64; k <<= 1) {
#pragma unroll
        for (int j = k >> 1; j >= 1; j >>= 1) {
            double ov = __shfl_xor(v, j);
            int oi = __shfl_xor(oid, j);
            bool amLow = (lane & j) == 0;
            bool asc = (lane & k) == 0;
            bool gt = (ov > v) || (ov == v && oi < oid);
            bool ga = gt != amLow;
            bool take = asc ? ga : !ga;
            if (take) { v = ov; oid = oi; }
        }
    }
    if (lane >= 32) idxout[((size_t)b * NPTS + n) * 32 + (63 - lane)] = oid;
}

// ---------------- feature transpose [B,64,N] -> bf16 [B,N,64] --------------
__global__ __launch_bounds__(256) void transpose_kernel(const float* __restrict__ feat,
                                                        unsigned short* __restrict__ fTb) {
    __shared__ float tile[64][65];
    int b = blockIdx.x / 32;
    int n0 = (blockIdx.x % 32) * 64;
    int t = threadIdx.x;
    int nt = t % 64, cg = t / 64;
    for (int cc = 0; cc < 16; cc++) {
        int c2 = cg * 16 + cc;
        tile[c2][nt] = feat[((size_t)b * 64 + c2) * NPTS + n0 + nt];
    }
    __syncthreads();
    int c2 = t % 64, ng = t / 64;
    for (int nn2 = 0; nn2 < 16; nn2++) {
        int n = ng * 16 + nn2;
        fTb[((size_t)b * NPTS + n0 + n) * 64 + c2] = f2bf(tile[c2][n]);
    }
}

// ---- weight prep: fold group-shuffle + MLP into WtT[oc][4096] bf16 --------
__global__ __launch_bounds__(256) void wprep2_kernel(
    const float* __restrict__ cw, const float* __restrict__ mlpw,
    const float* __restrict__ mb, const float* __restrict__ cb,
    unsigned short* __restrict__ WtT, float* __restrict__ cbw) {
    int oc = blockIdx.x;
    int t = threadIdx.x;
    for (int i = t; i < 2048; i += 256) {
        int f = i >> 5, col = i & 31;
        int r = (f % 24) * 4 + f / 24;
        WtT[(size_t)oc * KROW + i] = f2bf(cw[(size_t)oc * 3072 + r * 32 + col]);
    }
    for (int i = t; i < 2048; i += 256) {
        int j = i >> 5, col = i & 31;
        float s = 0.f;
        for (int o2 = 0; o2 < 32; o2++) {
            int f = 64 + o2;
            int r = (f % 24) * 4 + f / 24;
            s = fmaf(mlpw[o2 * 64 + j], cw[(size_t)oc * 3072 + r * 32 + col], s);
        }
        WtT[(size_t)oc * KROW + 2048 + i] = f2bf(s);
    }
    if (t == 0) {
        float s = cb[oc];
        for (int o2 = 0; o2 < 32; o2++) {
            int f = 64 + o2;
            int r = (f % 24) * 4 + f / 24;
            float rowsum = 0.f;
            for (int col = 0; col < 32; col++) rowsum += cw[(size_t)oc * 3072 + r * 32 + col];
            s = fmaf(mb[o2], rowsum, s);
        }
        cbw[oc] = s;
    }
}

__global__ void kprep_kernel(const float* __restrict__ ker, double* __restrict__ kerd) {
    int i = threadIdx.x;
    if (i < 96) kerd[i] = (double)ker[i];
}

// ---- perm kernel: 2 points/wave; fp64 p + top3 + softmax -> PTws bf16 ----
__global__ __launch_bounds__(256) void perm_kernel(
    const float* __restrict__ x, const int* __restrict__ idx,
    const double* __restrict__ kerd, unsigned short* __restrict__ PTws) {
    int t = threadIdx.x;
    int wv = t >> 6, l = t & 63;
    int c = l & 31;
    int cbase = l & 32;               // 0 for point A lanes, 32 for point B lanes
    int m = blockIdx.x * 8 + wv * 2 + (l >> 5);
    int b = m >> 11;
    int ik = idx[(size_t)m * 32 + c];
    const float* xb = x + (size_t)b * 3 * NPTS;
    float nx0 = xb[ik], ny0 = xb[NPTS + ik], nz0 = xb[2 * NPTS + ik];
    float cx = __shfl(nx0, cbase), cy = __shfl(ny0, cbase), cz = __shfl(nz0, cbase);
    double rxd = (double)nx0 - (double)cx;
    double ryd = (double)ny0 - (double)cy;
    double rzd = (double)nz0 - (double)cz;
    double ck0 = kerd[c], ck1 = kerd[32 + c], ck2 = kerd[64 + c];

    // p column c of own point: row kk's x_rel broadcast from lane cbase+kk
    double pd[32];
#pragma unroll
    for (int kk = 0; kk < 32; kk++) {
        double bx = __shfl(rxd, cbase + kk);
        double by = __shfl(ryd, cbase + kk);
        double bz = __shfl(rzd, cbase + kk);
        pd[kk] = bx * ck0 + by * ck1 + bz * ck2;
    }
    if (c == 0) pd[0] += 1.0;   // one_pad at (row 0, col 0), per point

    // branchless fp64 top-3
    double m1 = -1.0e300, m2 = -1.0e300, m3 = -1.0e300;
#pragma unroll
    for (int kk = 0; kk < 32; kk++) {
        double v = pd[kk];
        double t2 = fmin(v, m1);
        double t3 = fmin(v, m2);
        m1 = fmax(m1, v);
        m2 = fmax(m2, t2);
        m3 = fmax(m3, t3);
    }
    // fp64-exact threshold, fp32 softmax
    float pv[32];
    float ssum = 0.f;
#pragma unroll
    for (int kk = 0; kk < 32; kk++) {
        float e = (pd[kk] >= m3) ? __expf((float)(pd[kk] - m1)) : 0.f;
        pv[kk] = e; ssum += e;
    }
    float rs = 1.f / ssum;
#pragma unroll
    for (int kk = 0; kk < 32; kk++) pv[kk] *= rs;

    // pack row c (k-contiguous bf16) and store to PTws[m][c][0..31]
    unsigned w[16];
#pragma unroll
    for (int i = 0; i < 16; i++)
        w[i] = pk2bf(pv[2 * i], pv[2 * i + 1]);
    size_t obase = (size_t)m * 1024 + (size_t)c * 32;
    *(uint4*)&PTws[obase]      = make_uint4(w[0], w[1], w[2], w[3]);
    *(uint4*)&PTws[obase + 8]  = make_uint4(w[4], w[5], w[6], w[7]);
    *(uint4*)&PTws[obase + 16] = make_uint4(w[8], w[9], w[10], w[11]);
    *(uint4*)&PTws[obase + 24] = make_uint4(w[12], w[13], w[14], w[15]);
}

// ------- point3: gather + fourier + O=G*perm (MFMA); perm from PTws -------
__global__ __launch_bounds__(256) void point3_kernel(
    const float* __restrict__ x, const unsigned short* __restrict__ fTb,
    const int* __restrict__ idx, const float* __restrict__ Bm,
    const unsigned short* __restrict__ PTws, unsigned short* __restrict__ Aof,
    int m_base, int m_count) {
    __shared__ __align__(16) unsigned short lds2[4 * 2560];  // G2 only: 20480 B/block
    int t = threadIdx.x;
    int wv = t >> 6, l = t & 63;
    int k = l & 31, h = l >> 5;
    unsigned short* G2 = lds2 + wv * 2560;   // [64][40] bf16 (5120 B)
    int lr = l & 15, lq = l >> 4;
    int gw = blockIdx.x * 4 + wv;
    int nw = gridDim.x * 4;

    for (int mi = gw; mi < m_count; mi += nw) {
        int m = m_base + mi;
        int b = m >> 11;
        int ik = idx[(size_t)m * 32 + k];
        const float* xb = x + (size_t)b * 3 * NPTS;
        float nx0 = xb[ik], ny0 = xb[NPTS + ik], nz0 = xb[2 * NPTS + ik];
        // hoisted loads: features + perm fragments
        const unsigned short* fr = fTb + (((size_t)b * NPTS + ik) * 64 + h * 32);
        uint4 f0 = *(const uint4*)fr;
        uint4 f1 = *(const uint4*)(fr + 8);
        uint4 f2 = *(const uint4*)(fr + 16);
        uint4 f3 = *(const uint4*)(fr + 24);
        const unsigned short* ptp = PTws + (size_t)m * 1024;
        bf16x8 af0 = *(const bf16x8*)&ptp[lr * 32 + lq * 8];
        bf16x8 af1 = *(const bf16x8*)&ptp[(16 + lr) * 32 + lq * 8];

        float cx = __shfl(nx0, 0), cy = __shfl(ny0, 0), cz = __shfl(nz0, 0);
        float rx = nx0 - cx, ry = ny0 - cy, rz = nz0 - cz;
        float dist = sqrtf((rx * rx + ry * ry) + rz * rz);

        // G2 pass 1: gathered neighbor features rows 0..63, pair-pack across k
        {
            unsigned fw[16] = {f0.x, f0.y, f0.z, f0.w, f1.x, f1.y, f1.z, f1.w,
                               f2.x, f2.y, f2.z, f2.w, f3.x, f3.y, f3.z, f3.w};
#pragma unroll
            for (int c2 = 0; c2 < 16; c2++) {
                unsigned v = fw[c2];
                unsigned o = (unsigned)__shfl_xor((int)v, 1);
                unsigned wr = (k & 1) ? ((o >> 16) | (v & 0xFFFF0000u))
                                      : ((v & 0xFFFFu) | (o << 16));
                int ch = h * 32 + 2 * c2 + (k & 1);
                *(unsigned*)&G2[ch * 40 + (k & ~1)] = wr;
            }
        }
        asm volatile("" ::: "memory");

        // MFMA pass 1: O rows 0..63 (feats)
        size_t obase = (size_t)mi * KROW;
#pragma unroll
        for (int fb = 0; fb < 4; fb++) {
            int row = fb * 16 + lr;
            bf16x8 bfr = *(const bf16x8*)&G2[row * 40 + lq * 8];
            f32x4 d0 = __builtin_amdgcn_mfma_f32_16x16x32_bf16(af0, bfr, (f32x4){0.f, 0.f, 0.f, 0.f}, 0, 0, 0);
            f32x4 d1 = __builtin_amdgcn_mfma_f32_16x16x32_bf16(af1, bfr, (f32x4){0.f, 0.f, 0.f, 0.f}, 0, 0, 0);
            *(uint2*)&Aof[obase + row * 32 + lq * 4] =
                make_uint2(pk2bf(d0.x, d0.y), pk2bf(d0.z, d0.w));
            *(uint2*)&Aof[obase + row * 32 + 16 + lq * 4] =
                make_uint2(pk2bf(d1.x, d1.y), pk2bf(d1.z, d1.w));
        }
        asm volatile("" ::: "memory");

        // G2 pass 2: Fourier features rows 0..63 (sin 0..31, cos 32..63)
        {
            float u[32];
#pragma unroll
            for (int f = 0; f < 32; f++) {
                float uu = cx * Bm[f];
                uu = fmaf(cy, Bm[32 + f], uu);
                uu = fmaf(cz, Bm[64 + f], uu);
                uu = fmaf(rx, Bm[96 + f], uu);
                uu = fmaf(ry, Bm[128 + f], uu);
                uu = fmaf(rz, Bm[160 + f], uu);
                uu = fmaf(dist, Bm[192 + f], uu);
                u[f] = 6.28318530717958647692f * uu;
            }
            float tv[32];
            if (h == 0) {
#pragma unroll
                for (int f = 0; f < 32; f++) tv[f] = __sinf(u[f]);
            } else {
#pragma unroll
                for (int f = 0; f < 32; f++) tv[f] = __cosf(u[f]);
            }
#pragma unroll
            for (int jj = 0; jj < 16; jj++) {
                float o0 = __shfl_xor(tv[jj], 1);
                float o1 = __shfl_xor(tv[jj + 16], 1);
                float lo = (k & 1) ? o1 : tv[jj];
                float hi = (k & 1) ? tv[jj + 16] : o0;
                unsigned wr = pk2bf(lo, hi);
                int row = h * 32 + (k & 1) * 16 + jj;
                *(unsigned*)&G2[row * 40 + (k & ~1)] = wr;
            }
        }
        asm volatile("" ::: "memory");

        // MFMA pass 2: O rows 64..127
#pragma unroll
        for (int fb = 0; fb < 4; fb++) {
            int row = fb * 16 + lr;
            bf16x8 bfr = *(const bf16x8*)&G2[row * 40 + lq * 8];
            f32x4 d0 = __builtin_amdgcn_mfma_f32_16x16x32_bf16(af0, bfr, (f32x4){0.f, 0.f, 0.f, 0.f}, 0, 0, 0);
            f32x4 d1 = __builtin_amdgcn_mfma_f32_16x16x32_bf16(af1, bfr, (f32x4){0.f, 0.f, 0.f, 0.f}, 0, 0, 0);
            int f = 64 + row;
            *(uint2*)&Aof[obase + f * 32 + lq * 4] =
                make_uint2(pk2bf(d0.x, d0.y), pk2bf(d0.z, d0.w));
            *(uint2*)&Aof[obase + f * 32 + 16 + lq * 4] =
                make_uint2(pk2bf(d1.x, d1.y), pk2bf(d1.z, d1.w));
        }
        asm volatile("" ::: "memory");
    }
}

// ---------------- conv GEMM (MFMA): out = Aof[CSx4096] * Wtot --------------
__global__ __launch_bounds__(256) void conv2_kernel(
    const unsigned short* __restrict__ A, const unsigned short* __restrict__ WtT,
    const float* __restrict__ cbw, float* __restrict__ outp, int m_base) {
    __shared__ unsigned short Al[64 * 72];
    __shared__ unsigned short Wl[64 * 72];
    int t = threadIdx.x;
    int wv = t >> 6, l = t & 63;
    int lr = l & 15, lq = l >> 4;
    int m0 = blockIdx.x * 64;
    int mr = t >> 3, kq = t & 7;
    f32x4 acc[4] = {};
    for (int ks = 0; ks < 64; ks++) {
        int k0 = ks * 64;
        uint4 a0 = *(const uint4*)&A[(size_t)(m0 + mr) * KROW + k0 + kq * 8];
        uint4 a1 = *(const uint4*)&A[(size_t)(m0 + mr + 32) * KROW + k0 + kq * 8];
        uint4 w0 = *(const uint4*)&WtT[(size_t)mr * KROW + k0 + kq * 8];
        uint4 w1 = *(const uint4*)&WtT[(size_t)(mr + 32) * KROW + k0 + kq * 8];
        __syncthreads();
        *(uint4*)&Al[mr * 72 + kq * 8] = a0;
        *(uint4*)&Al[(mr + 32) * 72 + kq * 8] = a1;
        *(uint4*)&Wl[mr * 72 + kq * 8] = w0;
        *(uint4*)&Wl[(mr + 32) * 72 + kq * 8] = w1;
        __syncthreads();
#pragma unroll
        for (int kk = 0; kk < 2; kk++) {
            bf16x8 af = *(const bf16x8*)&Al[(wv * 16 + lr) * 72 + kk * 32 + lq * 8];
#pragma unroll
            for (int ocb = 0; ocb < 4; ocb++) {
                bf16x8 wf = *(const bf16x8*)&Wl[(ocb * 16 + lr) * 72 + kk * 32 + lq * 8];
                acc[ocb] = __builtin_amdgcn_mfma_f32_16x16x32_bf16(af, wf, acc[ocb], 0, 0, 0);
            }
        }
    }
    int m = m_base + m0 + wv * 16 + lq * 4;
    int b = m >> 11, n = m & 2047;
#pragma unroll
    for (int ocb = 0; ocb < 4; ocb++) {
        int oc = ocb * 16 + lr;
        float bias = cbw[oc];
        float4 v = make_float4(acc[ocb].x + bias, acc[ocb].y + bias,
                               acc[ocb].z + bias, acc[ocb].w + bias);
        *(float4*)&outp[((size_t)(b * 64 + oc)) * 2048 + n] = v;
    }
}

// ---------------- BatchNorm -----------------------------------------------
__global__ __launch_bounds__(256) void bn1_kernel(const float* __restrict__ outp,
                                                  float* __restrict__ sums) {
    int c = blockIdx.x, t = threadIdx.x;
    float s = 0.0f, s2 = 0.0f;
    for (int b = 0; b < NBATCH; b++) {
        const float* p = outp + ((size_t)b * 64 + c) * NPTS;
        for (int i = t; i < NPTS; i += 256) {
            float v = p[i];
            s += v; s2 = fmaf(v, v, s2);
        }
    }
    __shared__ float r1[256], r2[256];
    r1[t] = s; r2[t] = s2;
    __syncthreads();
    for (int st = 128; st > 0; st >>= 1) {
        if (t < st) { r1[t] += r1[t + st]; r2[t] += r2[t + st]; }
        __syncthreads();
    }
    if (t == 0) { sums[c] = r1[0]; sums[64 + c] = r2[0]; }
}

__global__ __launch_bounds__(256) void bn2_kernel(float* __restrict__ outp,
                                                  const float* __restrict__ sums,
                                                  const float* __restrict__ gamma,
                                                  const float* __restrict__ beta) {
    int i = blockIdx.x * 256 + threadIdx.x;
    if (i >= MTOT * 64) return;
    int c = (i >> 11) & 63;
    float mean = sums[c] * (1.0f / (float)MTOT);
    float var = sums[64 + c] * (1.0f / (float)MTOT) - mean * mean;
    float inv = rsqrtf(var + 1e-5f);
    outp[i] = fmaf(gamma[c], (outp[i] - mean) * inv, beta[c]);
}

extern "C" void kernel_launch(void* const* d_in, const int* in_sizes, int n_in,
                              void* d_out, int out_size, void* d_ws, size_t ws_size,
                              hipStream_t stream) {
    (void)in_sizes; (void)n_in; (void)out_size;
    const float* x    = (const float*)d_in[0];
    const float* fea  = (const float*)d_in[1];
    const float* Bm   = (const float*)d_in[2];
    const float* ker  = (const float*)d_in[3];
    const float* mw   = (const float*)d_in[4];
    const float* mb   = (const float*)d_in[5];
    const float* cw   = (const float*)d_in[6];
    const float* cb   = (const float*)d_in[7];
    const float* gam  = (const float*)d_in[8];
    const float* bet  = (const float*)d_in[9];
    float* outp = (float*)d_out;

    char* wsb = (char*)d_ws;
    size_t off = 0;
    auto carve = [&](size_t sz) {
        void* p = wsb + off;
        off = (off + sz + 255) & ~(size_t)255;
        return p;
    };
    unsigned short* fTb  = (unsigned short*)carve((size_t)MTOT * 64 * 2);
    int*            idxw = (int*)carve((size_t)MTOT * 32 * 4);
    unsigned short* WtT  = (unsigned short*)carve((size_t)OUTC * KROW * 2);
    float*          cbw  = (float*)carve(64 * 4);
    double*         kerd = (double*)carve(96 * 8);
    float*          sums = (float*)carve(2 * 64 * 4);
    unsigned short* PTws = (unsigned short*)carve((size_t)MTOT * 1024 * 2);  // 32 MB
    size_t fixedEnd = off;
    int CS = 16384;
    while (fixedEnd + (size_t)CS * KROW * 2 > ws_size && CS > 2048) CS >>= 1;
    unsigned short* Aof = (unsigned short*)(wsb + fixedEnd);

    knn_kernel<<<NBATCH * (NPTS / 8), 512, 0, stream>>>(x, idxw);
    transpose_kernel<<<NBATCH * 32, 256, 0, stream>>>(fea, fTb);
    wprep2_kernel<<<64, 256, 0, stream>>>(cw, mw, mb, cb, WtT, cbw);
    kprep_kernel<<<1, 128, 0, stream>>>(ker, kerd);
    perm_kernel<<<MTOT / 8, 256, 0, stream>>>(x, idxw, kerd, PTws);

    for (int c0 = 0; c0 < MTOT; c0 += CS) {
        point3_kernel<<<1536, 256, 0, stream>>>(x, fTb, idxw, Bm, PTws, Aof, c0, CS);
        conv2_kernel<<<CS / 64, 256, 0, stream>>>(Aof, WtT, cbw, outp, c0);
    }
    bn1_kernel<<<64, 256, 0, stream>>>(outp, sums);
    bn2_kernel<<<(MTOT * 64 + 255) / 256, 256, 0, stream>>>(outp, sums, gam, bet);
}